// Round 13
// baseline (367.329 us; speedup 1.0000x reference)
//
#include <hip/hip_runtime.h>
#include <float.h>

#define NEG_SLOPE 0.2f

constexpr int N_NODES = 20000;
constexpr int NE      = 320000;
constexpr int H       = 8;
constexpr int D       = 32;
constexpr int HD      = 256;   // H*D
constexpr int FIN     = 256;
constexpr int SCAN_NT = 3 * N_NODES;           // 60000
constexpr int SCAN_NB = (SCAN_NT + 511) / 512; // 118
constexpr int FSZi    = N_NODES * HD;          // 5,120,000

typedef __attribute__((ext_vector_type(8))) short bf16x8;
typedef __attribute__((ext_vector_type(4))) float f32x4;

// ---- bf16 helpers (RNE) ----
__device__ __forceinline__ unsigned short f2bf(float x) {
    unsigned u = __float_as_uint(x);
    unsigned r = 0x7FFFu + ((u >> 16) & 1u);
    return (unsigned short)((u + r) >> 16);
}
__device__ __forceinline__ float bf2f(unsigned short h) {
    return __uint_as_float(((unsigned)h) << 16);
}

// ============ fused prep: cvt(xA,xB) | W1 transpose->bf16 | bias | wlr1 | wlr2 ============
// block roles by blockIdx.x:
//  [0,10000)          : cvt xA|xB (1024 floats per block)
//  [10000,10192)      : W1bT[z][n][k] = bf16(W1[z][k][n])
//  10192              : bias sums (tid<128)
//  [10193,10241)      : wlr1 (K=256)
//  [10241,10247)      : wlr2 (K=32)
__device__ __forceinline__ void wlr_calc(const float* W, const float* al,
                                         const float* ar, float* wlr,
                                         int K, int wstride, int t)
{
    int half = t / (3 * K * H);
    int rem  = t % (3 * K * H);
    int et = rem / (K * H);
    int rem2 = rem % (K * H);
    int k = rem2 / H, h = rem2 % H;
    const float* av = (half ? ar : al) + et * HD + h * D;
    const float* Wp = W + (size_t)et * wstride + k * HD + h * D;
    float s = 0.f;
#pragma unroll
    for (int d = 0; d < D; d++) s += Wp[d] * av[d];
    wlr[t] = s;
}

__global__ __launch_bounds__(256) void prep(
    const float* __restrict__ xA, const float* __restrict__ xB,
    const float* __restrict__ W1, const float* __restrict__ al1,
    const float* __restrict__ ar1, const float* __restrict__ b1,
    const float* __restrict__ W2, const float* __restrict__ al2,
    const float* __restrict__ ar2, const float* __restrict__ b2,
    unsigned short* __restrict__ xAb, unsigned short* __restrict__ xBb,
    unsigned short* __restrict__ W1bT, float* __restrict__ bs,
    float* __restrict__ wlr, float* __restrict__ wlr2)
{
    const int bid = blockIdx.x;
    const int tid = threadIdx.x;
    if (bid < 10000) {
        int t = bid * 1024 + tid * 4;
        const float* in; unsigned short* outp; int o;
        if (t < FSZi) { in = xA; outp = xAb; o = t; }
        else          { in = xB; outp = xBb; o = t - FSZi; }
        float4 v = *(const float4*)(in + o);
        ushort4 ob;
        ob.x = f2bf(v.x); ob.y = f2bf(v.y); ob.z = f2bf(v.z); ob.w = f2bf(v.w);
        *(ushort4*)(outp + o) = ob;
    } else if (bid < 10192) {
        int idx = (bid - 10000) * 256 + tid;          // [0,49152)
        int z = idx / 16384, rem = idx % 16384;
        int n = rem / 64, k4 = rem % 64;
        const float* Wz = W1 + (size_t)z * 65536;
        ushort4 ob;
        ob.x = f2bf(Wz[(k4 * 4 + 0) * 256 + n]);
        ob.y = f2bf(Wz[(k4 * 4 + 1) * 256 + n]);
        ob.z = f2bf(Wz[(k4 * 4 + 2) * 256 + n]);
        ob.w = f2bf(Wz[(k4 * 4 + 3) * 256 + n]);
        *(ushort4*)(W1bT + (size_t)z * 65536 + n * 256 + k4 * 4) = ob;
    } else if (bid == 10192) {
        if (tid < 128) {
            int which = tid >> 5, d = tid & 31;
            const float* b = (which < 2) ? b1 : b2;
            float s = 0.f;
            if (which & 1) {
#pragma unroll
                for (int h = 0; h < H; h++) s += b[0 * 256 + h * D + d];
            } else {
#pragma unroll
                for (int h = 0; h < H; h++) s += b[1 * 256 + h * D + d] + b[2 * 256 + h * D + d];
            }
            bs[tid] = s;
        }
    } else if (bid < 10241) {
        int t = (bid - 10193) * 256 + tid;            // [0,12288)
        wlr_calc(W1, al1, ar1, wlr, 256, 65536, t);
    } else {
        int t = (bid - 10241) * 256 + tid;            // [0,1536)
        wlr_calc(W2, al2, ar2, wlr2, 32, 8192, t);
    }
}

// ============ layer-1 fused: z<3 MFMA GEMM, z==3 el/er GEMVs ============
__global__ __launch_bounds__(256) void l1_fused(
    const unsigned short* __restrict__ xAb, const unsigned short* __restrict__ xBb,
    const unsigned short* __restrict__ W1bT, unsigned short* __restrict__ Fb,
    const float* __restrict__ xA, const float* __restrict__ xB,
    const float* __restrict__ wlr, float* __restrict__ el, float* __restrict__ er,
    int M)
{
    __shared__ __align__(16) unsigned char smem[32768];
    const int tid = threadIdx.x;
    const int z = blockIdx.z;

    if (z < 3) {
        const unsigned short* Xb = (z == 1) ? xBb : xAb;
        const unsigned short* WzT = W1bT + (size_t)z * 65536;
        unsigned short* F = Fb + (size_t)z * FSZi;
        unsigned short (*Xs)[40]  = (unsigned short (*)[40])smem;          // 10240 B
        unsigned short (*WsT)[40] = (unsigned short (*)[40])(smem + 10240); // 5120 B
        const int wid = tid >> 6, lane = tid & 63;
        const int r0 = blockIdx.x * 128;
        const int c0 = blockIdx.y * 64;
        const int l15 = lane & 15, lg = lane >> 4;

        f32x4 acc[2][4];
#pragma unroll
        for (int i = 0; i < 2; i++)
#pragma unroll
            for (int j = 0; j < 4; j++) acc[i][j] = (f32x4){0.f, 0.f, 0.f, 0.f};

        for (int kc = 0; kc < FIN; kc += 32) {
            for (int i = tid; i < 128 * 4; i += 256) {
                int row = i >> 2, q = i & 3;
                int grow = r0 + row;
                int4 xv = (grow < M) ? *(const int4*)(Xb + (size_t)grow * FIN + kc + q * 8)
                                     : make_int4(0, 0, 0, 0);
                *(int4*)&Xs[row][q * 8] = xv;
            }
            {   // b128 staging from pre-transposed W
                int n = tid >> 2, k8 = (tid & 3) * 8;
                int4 wv = *(const int4*)(WzT + (size_t)(c0 + n) * 256 + kc + k8);
                *(int4*)&WsT[n][k8] = wv;
            }
            __syncthreads();
            const int rm = wid * 32;
            bf16x8 a0 = *(const bf16x8*)&Xs[rm + l15][lg * 8];
            bf16x8 a1 = *(const bf16x8*)&Xs[rm + 16 + l15][lg * 8];
#pragma unroll
            for (int j = 0; j < 4; j++) {
                bf16x8 b = *(const bf16x8*)&WsT[j * 16 + l15][lg * 8];
                acc[0][j] = __builtin_amdgcn_mfma_f32_16x16x32_bf16(a0, b, acc[0][j], 0, 0, 0);
                acc[1][j] = __builtin_amdgcn_mfma_f32_16x16x32_bf16(a1, b, acc[1][j], 0, 0, 0);
            }
            __syncthreads();
        }
        const int rm = wid * 32;
#pragma unroll
        for (int i = 0; i < 2; i++)
#pragma unroll
            for (int j = 0; j < 4; j++)
#pragma unroll
                for (int r = 0; r < 4; r++) {
                    int row = r0 + rm + i * 16 + lg * 4 + r;
                    if (row < M)
                        F[(size_t)row * 256 + c0 + j * 16 + l15] = f2bf(acc[i][j][r]);
                }
    } else {
        // GEMV units: flat block id in [0,628); units 0..1249
        float* w = (float*)smem;          // up to 4*2048 floats
        const int KH = 2048, NH = N_NODES * H;
        int flat = blockIdx.x + 157 * blockIdx.y;
        for (int unit = flat; unit < 1250; unit += 628) {
            int by = (unit >= 625), bx = unit - by * 625;
            if (by == 0) {
                for (int i = tid; i < KH; i += 256) {
                    w[0 * KH + i] = wlr[0 * KH + i];
                    w[1 * KH + i] = wlr[4 * KH + i];
                    w[2 * KH + i] = wlr[2 * KH + i];
                    w[3 * KH + i] = wlr[5 * KH + i];
                }
            } else {
                for (int i = tid; i < KH; i += 256) {
                    w[0 * KH + i] = wlr[1 * KH + i];
                    w[1 * KH + i] = wlr[3 * KH + i];
                }
            }
            __syncthreads();
            int t = bx * 256 + tid;               // < 160000 = N*H always
            int n = t >> 3, h = t & 7;
            const float4* xp = (const float4*)(((by == 0) ? xA : xB) + (size_t)n * FIN);
            if (by == 0) {
                float s0 = 0.f, s1 = 0.f, s2 = 0.f, s3 = 0.f;
#pragma unroll 2
                for (int k4 = 0; k4 < 64; k4++) {
                    float4 xv = xp[k4];
                    const float* xe = &xv.x;
#pragma unroll
                    for (int e = 0; e < 4; e++) {
                        int idx = (4 * k4 + e) * H + h;
                        float xx = xe[e];
                        s0 = fmaf(xx, w[0 * KH + idx], s0);
                        s1 = fmaf(xx, w[1 * KH + idx], s1);
                        s2 = fmaf(xx, w[2 * KH + idx], s2);
                        s3 = fmaf(xx, w[3 * KH + idx], s3);
                    }
                }
                el[t] = s0; er[NH + t] = s1; el[2 * NH + t] = s2; er[2 * NH + t] = s3;
            } else {
                float s0 = 0.f, s1 = 0.f;
#pragma unroll 2
                for (int k4 = 0; k4 < 64; k4++) {
                    float4 xv = xp[k4];
                    const float* xe = &xv.x;
#pragma unroll
                    for (int e = 0; e < 4; e++) {
                        int idx = (4 * k4 + e) * H + h;
                        float xx = xe[e];
                        s0 = fmaf(xx, w[0 * KH + idx], s0);
                        s1 = fmaf(xx, w[1 * KH + idx], s1);
                    }
                }
                el[NH + t] = s0; er[t] = s1;
            }
            __syncthreads();
        }
    }
}

// ============ layer-2 fused: z<3 fp32 GEMM (K=32), z==3 GEMVs ============
__global__ __launch_bounds__(256) void l2_fused(
    const float* __restrict__ hA, const float* __restrict__ hB,
    const float* __restrict__ W2, unsigned short* __restrict__ Fb,
    const float* __restrict__ wlr2, float* __restrict__ el, float* __restrict__ er,
    int M)
{
    __shared__ __align__(16) unsigned char smem[28672];
    const int tid = threadIdx.x;
    const int z = blockIdx.z;

    if (z < 3) {
        const float* X = (z == 1) ? hB : hA;
        const float* W = W2 + (size_t)z * 8192;
        unsigned short* F = Fb + (size_t)z * FSZi;
        float (*Xs)[40] = (float (*)[40])smem;                // 20480 B
        float (*Ws)[64] = (float (*)[64])(smem + 20480);      // 8192 B
        const int tx = tid & 15, ty = tid >> 4;
        const int r0 = blockIdx.x * 128;
        const int c0 = blockIdx.y * 64;
        for (int idx = tid; idx < 128 * 8; idx += 256) {
            int row = idx >> 3, kq = idx & 7;
            int grow = r0 + row;
            float4 xv = (grow < M) ? *(const float4*)(X + (size_t)grow * 32 + kq * 4)
                                   : make_float4(0.f, 0.f, 0.f, 0.f);
            *(float4*)&Xs[row][kq * 4] = xv;
        }
        for (int idx = tid; idx < 32 * 16; idx += 256) {
            int k = idx >> 4, cq = idx & 15;
            *(float4*)&Ws[k][cq * 4] = *(const float4*)(W + (size_t)k * 256 + c0 + cq * 4);
        }
        __syncthreads();
        float4 acc[8];
#pragma unroll
        for (int r = 0; r < 8; r++) acc[r] = make_float4(0.f, 0.f, 0.f, 0.f);
#pragma unroll 4
        for (int k = 0; k < 32; k++) {
            float4 wv = *(float4*)&Ws[k][tx * 4];
#pragma unroll
            for (int r = 0; r < 8; r++) {
                float x = Xs[ty + 16 * r][k];
                acc[r].x = fmaf(x, wv.x, acc[r].x);
                acc[r].y = fmaf(x, wv.y, acc[r].y);
                acc[r].z = fmaf(x, wv.z, acc[r].z);
                acc[r].w = fmaf(x, wv.w, acc[r].w);
            }
        }
#pragma unroll
        for (int r = 0; r < 8; r++) {
            int row = r0 + ty + 16 * r;
            if (row < M) {
                ushort4 cb;
                cb.x = f2bf(acc[r].x); cb.y = f2bf(acc[r].y);
                cb.z = f2bf(acc[r].z); cb.w = f2bf(acc[r].w);
                *(ushort4*)(F + (size_t)row * 256 + c0 + tx * 4) = cb;
            }
        }
    } else {
        float* w = (float*)smem;          // up to 4*256 floats
        const int KH = 256, NH = N_NODES * H;
        int flat = blockIdx.x + 157 * blockIdx.y;
        for (int unit = flat; unit < 1250; unit += 628) {
            int by = (unit >= 625), bx = unit - by * 625;
            if (by == 0) {
                for (int i = tid; i < KH; i += 256) {
                    w[0 * KH + i] = wlr2[0 * KH + i];
                    w[1 * KH + i] = wlr2[4 * KH + i];
                    w[2 * KH + i] = wlr2[2 * KH + i];
                    w[3 * KH + i] = wlr2[5 * KH + i];
                }
            } else {
                for (int i = tid; i < KH; i += 256) {
                    w[0 * KH + i] = wlr2[1 * KH + i];
                    w[1 * KH + i] = wlr2[3 * KH + i];
                }
            }
            __syncthreads();
            int t = bx * 256 + tid;
            int n = t >> 3, h = t & 7;
            const float4* xp = (const float4*)(((by == 0) ? hA : hB) + (size_t)n * 32);
            if (by == 0) {
                float s0 = 0.f, s1 = 0.f, s2 = 0.f, s3 = 0.f;
#pragma unroll
                for (int k4 = 0; k4 < 8; k4++) {
                    float4 xv = xp[k4];
                    const float* xe = &xv.x;
#pragma unroll
                    for (int e = 0; e < 4; e++) {
                        int idx = (4 * k4 + e) * H + h;
                        float xx = xe[e];
                        s0 = fmaf(xx, w[0 * KH + idx], s0);
                        s1 = fmaf(xx, w[1 * KH + idx], s1);
                        s2 = fmaf(xx, w[2 * KH + idx], s2);
                        s3 = fmaf(xx, w[3 * KH + idx], s3);
                    }
                }
                el[t] = s0; er[NH + t] = s1; el[2 * NH + t] = s2; er[2 * NH + t] = s3;
            } else {
                float s0 = 0.f, s1 = 0.f;
#pragma unroll
                for (int k4 = 0; k4 < 8; k4++) {
                    float4 xv = xp[k4];
                    const float* xe = &xv.x;
#pragma unroll
                    for (int e = 0; e < 4; e++) {
                        int idx = (4 * k4 + e) * H + h;
                        float xx = xe[e];
                        s0 = fmaf(xx, w[0 * KH + idx], s0);
                        s1 = fmaf(xx, w[1 * KH + idx], s1);
                    }
                }
                el[NH + t] = s0; er[t] = s1;
            }
            __syncthreads();
        }
    }
}

// ============ CSR build ============

__global__ void hist3(const int* __restrict__ v0, const int* __restrict__ v1,
                      const int* __restrict__ v2, int* __restrict__ cnt)
{
    int t = blockIdx.x * blockDim.x + threadIdx.x;
    if (t >= 3 * NE) return;
    int et = t / NE, i = t - et * NE;
    const int* vp = (et == 0) ? v0 : (et == 1) ? v1 : v2;
    atomicAdd(&cnt[et * N_NODES + vp[i]], 1);
}

__global__ __launch_bounds__(512) void scan_blk(
    const int* __restrict__ cnt, int* __restrict__ loc, int* __restrict__ bsum)
{
    int gid = blockIdx.x * 512 + threadIdx.x;
    int x = (gid < SCAN_NT) ? cnt[gid] : 0;
    int lane = threadIdx.x & 63, w = threadIdx.x >> 6;
    int v = x;
#pragma unroll
    for (int d = 1; d < 64; d <<= 1) {
        int y = __shfl_up(v, d, 64);
        if (lane >= d) v += y;
    }
    __shared__ int wsum[8];
    if (lane == 63) wsum[w] = v;
    __syncthreads();
    if (threadIdx.x == 0) {
        int run = 0;
#pragma unroll
        for (int i = 0; i < 8; i++) { int t2 = wsum[i]; wsum[i] = run; run += t2; }
    }
    __syncthreads();
    int excl = v - x + wsum[w];
    if (gid < SCAN_NT) loc[gid] = excl;
    if (threadIdx.x == 511) bsum[blockIdx.x] = excl + x;   // raw block total
}

// scan of raw bsum done redundantly per block (<=118 adds)
__global__ __launch_bounds__(512) void scan_add2(
    const int* __restrict__ loc, const int* __restrict__ bsum,
    int* __restrict__ off, int* __restrict__ cursor)
{
    int pre = 0;
    for (int i = 0; i < (int)blockIdx.x; i++) pre += bsum[i];
    int gid = blockIdx.x * 512 + threadIdx.x;
    if (gid < SCAN_NT) {
        int o = loc[gid] + pre;
        off[gid] = o;
        cursor[gid] = o;
    } else if (gid == SCAN_NT) {
        off[gid] = 3 * NE;
    }
}

__global__ void fill3(const int* __restrict__ u0, const int* __restrict__ v0,
                      const int* __restrict__ u1, const int* __restrict__ v1,
                      const int* __restrict__ u2, const int* __restrict__ v2,
                      int* __restrict__ cursor, int* __restrict__ usort)
{
    int t = blockIdx.x * blockDim.x + threadIdx.x;
    if (t >= 3 * NE) return;
    int et = t / NE, i = t - et * NE;
    const int* up = (et == 0) ? u0 : (et == 1) ? u1 : u2;
    const int* vp = (et == 0) ? v0 : (et == 1) ? v1 : v2;
    int pos = atomicAdd(&cursor[et * N_NODES + vp[i]], 1);
    usort[pos] = up[i];
}

// ============ fused edge softmax + gather + head-mean (bf16 F) ============

__device__ __forceinline__ float lrelu(float e) {
    return (e >= 0.f) ? e : NEG_SLOPE * e;
}

__device__ __forceinline__ float4 seg_accum(
    const float* __restrict__ el, float erh,
    const int* __restrict__ us, int lo, int hi,
    const unsigned short* __restrict__ Fs, int lane, int h)
{
    float4 aa = make_float4(0.f, 0.f, 0.f, 0.f);
    if (lo >= hi) return aa;
    const int q = lane & 7;
    const int lbase = lane & 56;   // h*8
    float s = 0.f;
    int j = lo;
    for (; j + 8 <= hi; j += 8) {
        int u[8];
#pragma unroll
        for (int qq = 0; qq < 8; qq++) u[qq] = us[j + qq];
        ushort4 fb[8];
#pragma unroll
        for (int qq = 0; qq < 8; qq++)
            fb[qq] = *(const ushort4*)(Fs + ((size_t)u[qq] << 8) + lane * 4);
        float myw = __expf(lrelu(el[u[q] * H + h] + erh));
#pragma unroll
        for (int qq = 0; qq < 8; qq++) {
            float w = __shfl(myw, lbase + qq, 64);
            s += w;
            aa.x = fmaf(w, bf2f(fb[qq].x), aa.x);
            aa.y = fmaf(w, bf2f(fb[qq].y), aa.y);
            aa.z = fmaf(w, bf2f(fb[qq].z), aa.z);
            aa.w = fmaf(w, bf2f(fb[qq].w), aa.w);
        }
    }
    if (j < hi) {
        int rem = hi - j;
        int u[8];
#pragma unroll
        for (int qq = 0; qq < 8; qq++) u[qq] = us[(qq < rem) ? j + qq : hi - 1];
        ushort4 fb[8];
#pragma unroll
        for (int qq = 0; qq < 8; qq++)
            fb[qq] = *(const ushort4*)(Fs + ((size_t)u[qq] << 8) + lane * 4);
        float myw = (q < rem) ? __expf(lrelu(el[u[q] * H + h] + erh)) : 0.f;
#pragma unroll
        for (int qq = 0; qq < 8; qq++) {
            float w = __shfl(myw, lbase + qq, 64);
            s += w;
            aa.x = fmaf(w, bf2f(fb[qq].x), aa.x);
            aa.y = fmaf(w, bf2f(fb[qq].y), aa.y);
            aa.z = fmaf(w, bf2f(fb[qq].z), aa.z);
            aa.w = fmaf(w, bf2f(fb[qq].w), aa.w);
        }
    }
    float inv = (s > 0.f) ? 1.f / s : 0.f;
    aa.x *= inv; aa.y *= inv; aa.z *= inv; aa.w *= inv;
    return aa;
}

template <int RELU>
__global__ __launch_bounds__(256) void seg_att_all(
    const float* __restrict__ el0, const float* __restrict__ er0,
    const int* __restrict__ off0, const unsigned short* __restrict__ F0,
    const float* __restrict__ el1, const float* __restrict__ er1,
    const int* __restrict__ off1, const unsigned short* __restrict__ F1,
    const float* __restrict__ el2, const float* __restrict__ er2,
    const int* __restrict__ off2, const unsigned short* __restrict__ F2,
    const int* __restrict__ us, const float* __restrict__ bsB,
    const float* __restrict__ bsA, float* __restrict__ outB,
    float* __restrict__ outA, int N)
{
    int wid = blockIdx.x * 4 + (threadIdx.x >> 6);
    if (wid >= 2 * N) return;
    const int lane = threadIdx.x & 63;
    const int h = lane >> 3;
    float4 tot;
    const float* bs;
    float* out;
    int v;
    if (wid < N) {
        v = wid;
        tot = seg_accum(el0, er0[v * H + h], us, off0[v], off0[v + 1], F0, lane, h);
        bs = bsB; out = outB;
    } else {
        v = wid - N;
        float4 t1 = seg_accum(el1, er1[v * H + h], us, off1[v], off1[v + 1], F1, lane, h);
        float4 t2 = seg_accum(el2, er2[v * H + h], us, off2[v], off2[v + 1], F2, lane, h);
        tot.x = t1.x + t2.x; tot.y = t1.y + t2.y;
        tot.z = t1.z + t2.z; tot.w = t1.w + t2.w;
        bs = bsA; out = outA;
    }
#pragma unroll
    for (int mask = 8; mask <= 32; mask <<= 1) {
        tot.x += __shfl_xor(tot.x, mask, 64);
        tot.y += __shfl_xor(tot.y, mask, 64);
        tot.z += __shfl_xor(tot.z, mask, 64);
        tot.w += __shfl_xor(tot.w, mask, 64);
    }
    if (lane < 8) {
        float4 b = *(const float4*)(bs + lane * 4);
        float4 o;
        o.x = (tot.x + b.x) * 0.125f;
        o.y = (tot.y + b.y) * 0.125f;
        o.z = (tot.z + b.z) * 0.125f;
        o.w = (tot.w + b.w) * 0.125f;
        if (RELU) {
            o.x = fmaxf(o.x, 0.f); o.y = fmaxf(o.y, 0.f);
            o.z = fmaxf(o.z, 0.f); o.w = fmaxf(o.w, 0.f);
        }
        *(float4*)(out + (size_t)v * D + lane * 4) = o;
    }
}

// ================= host =================

extern "C" void kernel_launch(void* const* d_in, const int* in_sizes, int n_in,
                              void* d_out, int out_size, void* d_ws, size_t ws_size,
                              hipStream_t stream)
{
    const float* xA  = (const float*)d_in[0];
    const float* xB  = (const float*)d_in[1];
    const float* W1  = (const float*)d_in[2];
    const float* al1 = (const float*)d_in[3];
    const float* ar1 = (const float*)d_in[4];
    const float* b1  = (const float*)d_in[5];
    const float* W2  = (const float*)d_in[6];
    const float* al2 = (const float*)d_in[7];
    const float* ar2 = (const float*)d_in[8];
    const float* b2  = (const float*)d_in[9];
    const int* u0 = (const int*)d_in[10];
    const int* v0 = (const int*)d_in[11];
    const int* u1 = (const int*)d_in[12];
    const int* v1 = (const int*)d_in[13];
    const int* u2 = (const int*)d_in[14];
    const int* v2 = (const int*)d_in[15];
    float* out = (float*)d_out;

    const size_t FSZ = (size_t)FSZi;
    unsigned short* xAb  = (unsigned short*)d_ws;
    unsigned short* xBb  = xAb + FSZ;
    unsigned short* Fb   = xBb + FSZ;              // [3][FSZ]
    unsigned short* F0b  = Fb;
    unsigned short* F1b  = Fb + FSZ;
    unsigned short* F2b  = Fb + 2 * FSZ;
    unsigned short* W1bT = Fb + 3 * FSZ;           // 196608
    float* el   = (float*)(W1bT + 3 * 65536);      // [3][N*H]
    float* er   = el + 3 * N_NODES * H;
    float* hA   = er + 3 * N_NODES * H;            // [N][32]
    float* hB   = hA + (size_t)N_NODES * D;
    float* wlr  = hB + (size_t)N_NODES * D;        // [6][2048]
    float* wlr2 = wlr + 6 * 2048;                  // [6][256]
    float* bs   = wlr2 + 6 * 256;                  // [4][32]
    int* off    = (int*)(bs + 128);                // 3N+1
    int* cursor = off + 3 * N_NODES + 1;
    int* cnt    = cursor + 3 * N_NODES;
    int* loc    = cnt + 3 * N_NODES;
    int* bsum   = loc + 3 * N_NODES;
    int* usort  = bsum + 128;                      // 3NE

    float* el0 = el, *el1p = el + N_NODES * H, *el2p = el + 2 * N_NODES * H;
    float* er0 = er, *er1p = er + N_NODES * H, *er2p = er + 2 * N_NODES * H;
    int* off0 = off, *off1 = off + N_NODES, *off2 = off + 2 * N_NODES;
    float* bsA1 = bs, *bsB1 = bs + 32, *bsA2 = bs + 64, *bsB2 = bs + 96;

    const dim3 GB_F(157, 4, 4);
    const int GB_ALL = (2 * N_NODES + 3) / 4;      // 10000
    const int GB_3E  = (3 * NE + 255) / 256;
    const int PREP_B = 10247;

    // ---- CSR build + prep ----
    hipMemsetAsync(cnt, 0, SCAN_NT * sizeof(int), stream);
    hist3<<<GB_3E, 256, 0, stream>>>(v0, v1, v2, cnt);
    scan_blk<<<SCAN_NB, 512, 0, stream>>>(cnt, loc, bsum);
    scan_add2<<<SCAN_NB, 512, 0, stream>>>(loc, bsum, off, cursor);
    fill3<<<GB_3E, 256, 0, stream>>>(u0, v0, u1, v1, u2, v2, cursor, usort);
    prep<<<PREP_B, 256, 0, stream>>>(xA, xB, W1, al1, ar1, b1, W2, al2, ar2, b2,
                                     xAb, xBb, W1bT, bs, wlr, wlr2);

    // ---------------- layer 1 ----------------
    l1_fused<<<GB_F, 256, 0, stream>>>(xAb, xBb, W1bT, Fb, xA, xB, wlr, el, er, N_NODES);
    seg_att_all<1><<<GB_ALL, 256, 0, stream>>>(el0, er0, off0, F0b,
                                               el1p, er1p, off1, F1b,
                                               el2p, er2p, off2, F2b,
                                               usort, bsB1, bsA1, hB, hA, N_NODES);

    // ---------------- layer 2 ----------------
    l2_fused<<<GB_F, 256, 0, stream>>>(hA, hB, W2, Fb, wlr2, el, er, N_NODES);
    seg_att_all<0><<<GB_ALL, 256, 0, stream>>>(el0, er0, off0, F0b,
                                               el1p, er1p, off1, F1b,
                                               el2p, er2p, off2, F2b,
                                               usort, bsB2, bsA2,
                                               out + (size_t)N_NODES * D, out, N_NODES);
}

// Round 14
// 361.295 us; speedup vs baseline: 1.0167x; 1.0167x over previous
//
#include <hip/hip_runtime.h>
#include <float.h>

#define NEG_SLOPE 0.2f

constexpr int N_NODES = 20000;
constexpr int NE      = 320000;
constexpr int H       = 8;
constexpr int D       = 32;
constexpr int HD      = 256;   // H*D
constexpr int FIN     = 256;
constexpr int SCAN_NT = 3 * N_NODES;           // 60000
constexpr int SCAN_NB = (SCAN_NT + 511) / 512; // 118
constexpr int FSZi    = N_NODES * HD;          // 5,120,000

typedef __attribute__((ext_vector_type(8))) short bf16x8;
typedef __attribute__((ext_vector_type(4))) float f32x4;

// ---- bf16 helpers (RNE) ----
__device__ __forceinline__ unsigned short f2bf(float x) {
    unsigned u = __float_as_uint(x);
    unsigned r = 0x7FFFu + ((u >> 16) & 1u);
    return (unsigned short)((u + r) >> 16);
}
__device__ __forceinline__ float bf2f(unsigned short h) {
    return __uint_as_float(((unsigned)h) << 16);
}

// ============ fused prep: cvt(xA,xB) | W1 transpose->bf16 | bias | wlr1 | wlr2 ============
__device__ __forceinline__ void wlr_calc(const float* W, const float* al,
                                         const float* ar, float* wlr,
                                         int K, int wstride, int t)
{
    int half = t / (3 * K * H);
    int rem  = t % (3 * K * H);
    int et = rem / (K * H);
    int rem2 = rem % (K * H);
    int k = rem2 / H, h = rem2 % H;
    const float* av = (half ? ar : al) + et * HD + h * D;
    const float* Wp = W + (size_t)et * wstride + k * HD + h * D;
    float s = 0.f;
#pragma unroll
    for (int d = 0; d < D; d++) s += Wp[d] * av[d];
    wlr[t] = s;
}

__global__ __launch_bounds__(256) void prep(
    const float* __restrict__ xA, const float* __restrict__ xB,
    const float* __restrict__ W1, const float* __restrict__ al1,
    const float* __restrict__ ar1, const float* __restrict__ b1,
    const float* __restrict__ W2, const float* __restrict__ al2,
    const float* __restrict__ ar2, const float* __restrict__ b2,
    unsigned short* __restrict__ xAb, unsigned short* __restrict__ xBb,
    unsigned short* __restrict__ W1bT, float* __restrict__ bs,
    float* __restrict__ wlr, float* __restrict__ wlr2)
{
    const int bid = blockIdx.x;
    const int tid = threadIdx.x;
    if (bid < 10000) {
        int t = bid * 1024 + tid * 4;
        const float* in; unsigned short* outp; int o;
        if (t < FSZi) { in = xA; outp = xAb; o = t; }
        else          { in = xB; outp = xBb; o = t - FSZi; }
        float4 v = *(const float4*)(in + o);
        ushort4 ob;
        ob.x = f2bf(v.x); ob.y = f2bf(v.y); ob.z = f2bf(v.z); ob.w = f2bf(v.w);
        *(ushort4*)(outp + o) = ob;
    } else if (bid < 10192) {
        int idx = (bid - 10000) * 256 + tid;          // [0,49152)
        int z = idx / 16384, rem = idx % 16384;
        int n = rem / 64, k4 = rem % 64;
        const float* Wz = W1 + (size_t)z * 65536;
        ushort4 ob;
        ob.x = f2bf(Wz[(k4 * 4 + 0) * 256 + n]);
        ob.y = f2bf(Wz[(k4 * 4 + 1) * 256 + n]);
        ob.z = f2bf(Wz[(k4 * 4 + 2) * 256 + n]);
        ob.w = f2bf(Wz[(k4 * 4 + 3) * 256 + n]);
        *(ushort4*)(W1bT + (size_t)z * 65536 + n * 256 + k4 * 4) = ob;
    } else if (bid == 10192) {
        if (tid < 128) {
            int which = tid >> 5, d = tid & 31;
            const float* b = (which < 2) ? b1 : b2;
            float s = 0.f;
            if (which & 1) {
#pragma unroll
                for (int h = 0; h < H; h++) s += b[0 * 256 + h * D + d];
            } else {
#pragma unroll
                for (int h = 0; h < H; h++) s += b[1 * 256 + h * D + d] + b[2 * 256 + h * D + d];
            }
            bs[tid] = s;
        }
    } else if (bid < 10241) {
        int t = (bid - 10193) * 256 + tid;            // [0,12288)
        wlr_calc(W1, al1, ar1, wlr, 256, 65536, t);
    } else {
        int t = (bid - 10241) * 256 + tid;            // [0,1536)
        wlr_calc(W2, al2, ar2, wlr2, 32, 8192, t);
    }
}

// ============ MFMA GEMM (z-batched): B direct from pre-transposed W (global->reg) ============
// 128x64 tile, BK=32, double-buffered X in LDS, B prefetched in registers.
__global__ __launch_bounds__(256) void mfma_gemm3(
    const unsigned short* __restrict__ xAb, const unsigned short* __restrict__ xBb,
    const unsigned short* __restrict__ W1bT, unsigned short* __restrict__ Fb, int M)
{
    const int z = blockIdx.z;
    const unsigned short* Xb = (z == 1) ? xBb : xAb;
    const unsigned short* WzT = W1bT + (size_t)z * 65536;
    unsigned short* F = Fb + (size_t)z * FSZi;

    __shared__ unsigned short Xs[2][128][40];
    const int tid = threadIdx.x;
    const int wid = tid >> 6, lane = tid & 63;
    const int r0 = blockIdx.x * 128;
    const int c0 = blockIdx.y * 64;
    const int l15 = lane & 15, lg = lane >> 4;

    f32x4 acc[2][4];
#pragma unroll
    for (int i = 0; i < 2; i++)
#pragma unroll
        for (int j = 0; j < 4; j++) acc[i][j] = (f32x4){0.f, 0.f, 0.f, 0.f};

    const int srow = tid >> 2, sq = tid & 3;        // stage: one int4 per thread x2
    bf16x8 bcur[4], bnxt[4];

    // stage s=0
    {
        int grow0 = r0 + srow, grow1 = r0 + srow + 64;
        *(int4*)&Xs[0][srow][sq * 8] =
            (grow0 < M) ? *(const int4*)(Xb + (size_t)grow0 * FIN + sq * 8) : make_int4(0,0,0,0);
        *(int4*)&Xs[0][srow + 64][sq * 8] =
            (grow1 < M) ? *(const int4*)(Xb + (size_t)grow1 * FIN + sq * 8) : make_int4(0,0,0,0);
    }
#pragma unroll
    for (int j = 0; j < 4; j++)
        bcur[j] = *(const bf16x8*)(WzT + (size_t)(c0 + j * 16 + l15) * 256 + lg * 8);
    __syncthreads();

    for (int s = 0; s < 8; s++) {
        int cur = s & 1, nb = cur ^ 1;
        if (s < 7) {
            int kc = (s + 1) * 32;
            int grow0 = r0 + srow, grow1 = r0 + srow + 64;
            *(int4*)&Xs[nb][srow][sq * 8] =
                (grow0 < M) ? *(const int4*)(Xb + (size_t)grow0 * FIN + kc + sq * 8) : make_int4(0,0,0,0);
            *(int4*)&Xs[nb][srow + 64][sq * 8] =
                (grow1 < M) ? *(const int4*)(Xb + (size_t)grow1 * FIN + kc + sq * 8) : make_int4(0,0,0,0);
#pragma unroll
            for (int j = 0; j < 4; j++)
                bnxt[j] = *(const bf16x8*)(WzT + (size_t)(c0 + j * 16 + l15) * 256 + kc + lg * 8);
        }
        const int rm = wid * 32;
        bf16x8 a0 = *(const bf16x8*)&Xs[cur][rm + l15][lg * 8];
        bf16x8 a1 = *(const bf16x8*)&Xs[cur][rm + 16 + l15][lg * 8];
#pragma unroll
        for (int j = 0; j < 4; j++) {
            acc[0][j] = __builtin_amdgcn_mfma_f32_16x16x32_bf16(a0, bcur[j], acc[0][j], 0, 0, 0);
            acc[1][j] = __builtin_amdgcn_mfma_f32_16x16x32_bf16(a1, bcur[j], acc[1][j], 0, 0, 0);
        }
        __syncthreads();
#pragma unroll
        for (int j = 0; j < 4; j++) bcur[j] = bnxt[j];
    }
    const int rm = wid * 32;
#pragma unroll
    for (int i = 0; i < 2; i++)
#pragma unroll
        for (int j = 0; j < 4; j++)
#pragma unroll
            for (int r = 0; r < 4; r++) {
                int row = r0 + rm + i * 16 + lg * 4 + r;
                if (row < M)
                    F[(size_t)row * 256 + c0 + j * 16 + l15] = f2bf(acc[i][j][r]);
            }
}

// ============ layer-2 vector GEMM (z-batched): F_z = X_z[M,32] @ W_z[32,256] ============
__global__ __launch_bounds__(256) void gemm32_3(
    const float* __restrict__ hA, const float* __restrict__ hB,
    const float* __restrict__ W2, unsigned short* __restrict__ Fb, int M)
{
    const int z = blockIdx.z;
    const float* X = (z == 1) ? hB : hA;
    const float* W = W2 + (size_t)z * 8192;
    unsigned short* F = Fb + (size_t)z * FSZi;

    __shared__ float Xs[128][40];
    __shared__ float Ws[32][64];
    const int tx = threadIdx.x & 15;
    const int ty = threadIdx.x >> 4;
    const int r0 = blockIdx.x * 128;
    const int c0 = blockIdx.y * 64;
    for (int idx = threadIdx.x; idx < 128 * 8; idx += 256) {
        int row = idx >> 3, kq = idx & 7;
        int grow = r0 + row;
        float4 xv = (grow < M) ? *(const float4*)(X + (size_t)grow * 32 + kq * 4)
                               : make_float4(0.f, 0.f, 0.f, 0.f);
        *(float4*)&Xs[row][kq * 4] = xv;
    }
    for (int idx = threadIdx.x; idx < 32 * 16; idx += 256) {
        int k = idx >> 4, cq = idx & 15;
        *(float4*)&Ws[k][cq * 4] = *(const float4*)(W + (size_t)k * 256 + c0 + cq * 4);
    }
    __syncthreads();
    float4 acc[8];
#pragma unroll
    for (int r = 0; r < 8; r++) acc[r] = make_float4(0.f, 0.f, 0.f, 0.f);
#pragma unroll 4
    for (int k = 0; k < 32; k++) {
        float4 wv = *(float4*)&Ws[k][tx * 4];
#pragma unroll
        for (int r = 0; r < 8; r++) {
            float x = Xs[ty + 16 * r][k];
            acc[r].x = fmaf(x, wv.x, acc[r].x);
            acc[r].y = fmaf(x, wv.y, acc[r].y);
            acc[r].z = fmaf(x, wv.z, acc[r].z);
            acc[r].w = fmaf(x, wv.w, acc[r].w);
        }
    }
#pragma unroll
    for (int r = 0; r < 8; r++) {
        int row = r0 + ty + 16 * r;
        if (row < M) {
            ushort4 cb;
            cb.x = f2bf(acc[r].x); cb.y = f2bf(acc[r].y);
            cb.z = f2bf(acc[r].z); cb.w = f2bf(acc[r].w);
            *(ushort4*)(F + (size_t)row * 256 + c0 + tx * 4) = cb;
        }
    }
}

// ---- fused GEMVs: grid.y==0: xa -> el0,er1,el2,er2 ; grid.y==1: xb -> el1,er0 ----
template <int K>
__global__ __launch_bounds__(256) void gemv6(
    const float* __restrict__ xa, const float* __restrict__ xb,
    const float* __restrict__ wlr,
    float* __restrict__ el, float* __restrict__ er, int N)
{
    __shared__ float w[4][K * H];
    const int KH = K * H;
    const int NH = N_NODES * H;
    float *o0, *o1, *o2, *o3;
    const float* x;
    if (blockIdx.y == 0) {
        for (int i = threadIdx.x; i < KH; i += 256) {
            w[0][i] = wlr[0 * KH + i];
            w[1][i] = wlr[4 * KH + i];
            w[2][i] = wlr[2 * KH + i];
            w[3][i] = wlr[5 * KH + i];
        }
        x = xa;
        o0 = el; o1 = er + NH; o2 = el + 2 * NH; o3 = er + 2 * NH;
    } else {
        for (int i = threadIdx.x; i < KH; i += 256) {
            w[0][i] = wlr[1 * KH + i];
            w[1][i] = wlr[3 * KH + i];
        }
        x = xb;
        o0 = el + NH; o1 = er; o2 = nullptr; o3 = nullptr;
    }
    __syncthreads();
    int t = blockIdx.x * 256 + threadIdx.x;
    if (t >= N * H) return;
    int n = t >> 3, h = t & 7;
    const float4* xp = (const float4*)(x + (size_t)n * K);
    float s0 = 0.f, s1 = 0.f, s2 = 0.f, s3 = 0.f;
    if (blockIdx.y == 0) {
#pragma unroll 2
        for (int k4 = 0; k4 < K / 4; k4++) {
            float4 xv = xp[k4];
            const float* xe = &xv.x;
#pragma unroll
            for (int e = 0; e < 4; e++) {
                int idx = (4 * k4 + e) * H + h;
                float xx = xe[e];
                s0 = fmaf(xx, w[0][idx], s0);
                s1 = fmaf(xx, w[1][idx], s1);
                s2 = fmaf(xx, w[2][idx], s2);
                s3 = fmaf(xx, w[3][idx], s3);
            }
        }
        o0[t] = s0; o1[t] = s1; o2[t] = s2; o3[t] = s3;
    } else {
#pragma unroll 2
        for (int k4 = 0; k4 < K / 4; k4++) {
            float4 xv = xp[k4];
            const float* xe = &xv.x;
#pragma unroll
            for (int e = 0; e < 4; e++) {
                int idx = (4 * k4 + e) * H + h;
                float xx = xe[e];
                s0 = fmaf(xx, w[0][idx], s0);
                s1 = fmaf(xx, w[1][idx], s1);
            }
        }
        o0[t] = s0; o1[t] = s1;
    }
}

// ============ CSR build ============

__global__ void hist3(const int* __restrict__ v0, const int* __restrict__ v1,
                      const int* __restrict__ v2, int* __restrict__ cnt)
{
    int t = blockIdx.x * blockDim.x + threadIdx.x;
    if (t >= 3 * NE) return;
    int et = t / NE, i = t - et * NE;
    const int* vp = (et == 0) ? v0 : (et == 1) ? v1 : v2;
    atomicAdd(&cnt[et * N_NODES + vp[i]], 1);
}

__global__ __launch_bounds__(512) void scan_blk(
    const int* __restrict__ cnt, int* __restrict__ loc, int* __restrict__ bsum)
{
    int gid = blockIdx.x * 512 + threadIdx.x;
    int x = (gid < SCAN_NT) ? cnt[gid] : 0;
    int lane = threadIdx.x & 63, w = threadIdx.x >> 6;
    int v = x;
#pragma unroll
    for (int d = 1; d < 64; d <<= 1) {
        int y = __shfl_up(v, d, 64);
        if (lane >= d) v += y;
    }
    __shared__ int wsum[8];
    if (lane == 63) wsum[w] = v;
    __syncthreads();
    if (threadIdx.x == 0) {
        int run = 0;
#pragma unroll
        for (int i = 0; i < 8; i++) { int t2 = wsum[i]; wsum[i] = run; run += t2; }
    }
    __syncthreads();
    int excl = v - x + wsum[w];
    if (gid < SCAN_NT) loc[gid] = excl;
    if (threadIdx.x == 511) bsum[blockIdx.x] = excl + x;
}

__global__ __launch_bounds__(512) void scan_add2(
    const int* __restrict__ loc, const int* __restrict__ bsum,
    int* __restrict__ off, int* __restrict__ cursor)
{
    int pre = 0;
    for (int i = 0; i < (int)blockIdx.x; i++) pre += bsum[i];
    int gid = blockIdx.x * 512 + threadIdx.x;
    if (gid < SCAN_NT) {
        int o = loc[gid] + pre;
        off[gid] = o;
        cursor[gid] = o;
    } else if (gid == SCAN_NT) {
        off[gid] = 3 * NE;
    }
}

__global__ void fill3(const int* __restrict__ u0, const int* __restrict__ v0,
                      const int* __restrict__ u1, const int* __restrict__ v1,
                      const int* __restrict__ u2, const int* __restrict__ v2,
                      int* __restrict__ cursor, int* __restrict__ usort)
{
    int t = blockIdx.x * blockDim.x + threadIdx.x;
    if (t >= 3 * NE) return;
    int et = t / NE, i = t - et * NE;
    const int* up = (et == 0) ? u0 : (et == 1) ? u1 : u2;
    const int* vp = (et == 0) ? v0 : (et == 1) ? v1 : v2;
    int pos = atomicAdd(&cursor[et * N_NODES + vp[i]], 1);
    usort[pos] = up[i];
}

// ============ fused edge softmax + gather + head-mean (bf16 F) ============

__device__ __forceinline__ float lrelu(float e) {
    return (e >= 0.f) ? e : NEG_SLOPE * e;
}

__device__ __forceinline__ float4 seg_accum(
    const float* __restrict__ el, float erh,
    const int* __restrict__ us, int lo, int hi,
    const unsigned short* __restrict__ Fs, int lane, int h)
{
    float4 aa = make_float4(0.f, 0.f, 0.f, 0.f);
    if (lo >= hi) return aa;
    const int q = lane & 7;
    const int lbase = lane & 56;   // h*8
    float s = 0.f;
    int j = lo;
    for (; j + 8 <= hi; j += 8) {
        int u[8];
#pragma unroll
        for (int qq = 0; qq < 8; qq++) u[qq] = us[j + qq];
        ushort4 fb[8];
#pragma unroll
        for (int qq = 0; qq < 8; qq++)
            fb[qq] = *(const ushort4*)(Fs + ((size_t)u[qq] << 8) + lane * 4);
        float myw = __expf(lrelu(el[u[q] * H + h] + erh));
#pragma unroll
        for (int qq = 0; qq < 8; qq++) {
            float w = __shfl(myw, lbase + qq, 64);
            s += w;
            aa.x = fmaf(w, bf2f(fb[qq].x), aa.x);
            aa.y = fmaf(w, bf2f(fb[qq].y), aa.y);
            aa.z = fmaf(w, bf2f(fb[qq].z), aa.z);
            aa.w = fmaf(w, bf2f(fb[qq].w), aa.w);
        }
    }
    if (j < hi) {
        int rem = hi - j;
        int u[8];
#pragma unroll
        for (int qq = 0; qq < 8; qq++) u[qq] = us[(qq < rem) ? j + qq : hi - 1];
        ushort4 fb[8];
#pragma unroll
        for (int qq = 0; qq < 8; qq++)
            fb[qq] = *(const ushort4*)(Fs + ((size_t)u[qq] << 8) + lane * 4);
        float myw = (q < rem) ? __expf(lrelu(el[u[q] * H + h] + erh)) : 0.f;
#pragma unroll
        for (int qq = 0; qq < 8; qq++) {
            float w = __shfl(myw, lbase + qq, 64);
            s += w;
            aa.x = fmaf(w, bf2f(fb[qq].x), aa.x);
            aa.y = fmaf(w, bf2f(fb[qq].y), aa.y);
            aa.z = fmaf(w, bf2f(fb[qq].z), aa.z);
            aa.w = fmaf(w, bf2f(fb[qq].w), aa.w);
        }
    }
    float inv = (s > 0.f) ? 1.f / s : 0.f;
    aa.x *= inv; aa.y *= inv; aa.z *= inv; aa.w *= inv;
    return aa;
}

template <int RELU>
__global__ __launch_bounds__(256) void seg_att_all(
    const float* __restrict__ el0, const float* __restrict__ er0,
    const int* __restrict__ off0, const unsigned short* __restrict__ F0,
    const float* __restrict__ el1, const float* __restrict__ er1,
    const int* __restrict__ off1, const unsigned short* __restrict__ F1,
    const float* __restrict__ el2, const float* __restrict__ er2,
    const int* __restrict__ off2, const unsigned short* __restrict__ F2,
    const int* __restrict__ us, const float* __restrict__ bsB,
    const float* __restrict__ bsA, float* __restrict__ outB,
    float* __restrict__ outA, int N)
{
    int wid = blockIdx.x * 4 + (threadIdx.x >> 6);
    if (wid >= 2 * N) return;
    const int lane = threadIdx.x & 63;
    const int h = lane >> 3;
    float4 tot;
    const float* bs;
    float* out;
    int v;
    if (wid < N) {
        v = wid;
        tot = seg_accum(el0, er0[v * H + h], us, off0[v], off0[v + 1], F0, lane, h);
        bs = bsB; out = outB;
    } else {
        v = wid - N;
        float4 t1 = seg_accum(el1, er1[v * H + h], us, off1[v], off1[v + 1], F1, lane, h);
        float4 t2 = seg_accum(el2, er2[v * H + h], us, off2[v], off2[v + 1], F2, lane, h);
        tot.x = t1.x + t2.x; tot.y = t1.y + t2.y;
        tot.z = t1.z + t2.z; tot.w = t1.w + t2.w;
        bs = bsA; out = outA;
    }
#pragma unroll
    for (int mask = 8; mask <= 32; mask <<= 1) {
        tot.x += __shfl_xor(tot.x, mask, 64);
        tot.y += __shfl_xor(tot.y, mask, 64);
        tot.z += __shfl_xor(tot.z, mask, 64);
        tot.w += __shfl_xor(tot.w, mask, 64);
    }
    if (lane < 8) {
        float4 b = *(const float4*)(bs + lane * 4);
        float4 o;
        o.x = (tot.x + b.x) * 0.125f;
        o.y = (tot.y + b.y) * 0.125f;
        o.z = (tot.z + b.z) * 0.125f;
        o.w = (tot.w + b.w) * 0.125f;
        if (RELU) {
            o.x = fmaxf(o.x, 0.f); o.y = fmaxf(o.y, 0.f);
            o.z = fmaxf(o.z, 0.f); o.w = fmaxf(o.w, 0.f);
        }
        *(float4*)(out + (size_t)v * D + lane * 4) = o;
    }
}

// ================= host =================

extern "C" void kernel_launch(void* const* d_in, const int* in_sizes, int n_in,
                              void* d_out, int out_size, void* d_ws, size_t ws_size,
                              hipStream_t stream)
{
    const float* xA  = (const float*)d_in[0];
    const float* xB  = (const float*)d_in[1];
    const float* W1  = (const float*)d_in[2];
    const float* al1 = (const float*)d_in[3];
    const float* ar1 = (const float*)d_in[4];
    const float* b1  = (const float*)d_in[5];
    const float* W2  = (const float*)d_in[6];
    const float* al2 = (const float*)d_in[7];
    const float* ar2 = (const float*)d_in[8];
    const float* b2  = (const float*)d_in[9];
    const int* u0 = (const int*)d_in[10];
    const int* v0 = (const int*)d_in[11];
    const int* u1 = (const int*)d_in[12];
    const int* v1 = (const int*)d_in[13];
    const int* u2 = (const int*)d_in[14];
    const int* v2 = (const int*)d_in[15];
    float* out = (float*)d_out;

    const size_t FSZ = (size_t)FSZi;
    unsigned short* xAb  = (unsigned short*)d_ws;
    unsigned short* xBb  = xAb + FSZ;
    unsigned short* Fb   = xBb + FSZ;              // [3][FSZ]
    unsigned short* F0b  = Fb;
    unsigned short* F1b  = Fb + FSZ;
    unsigned short* F2b  = Fb + 2 * FSZ;
    unsigned short* W1bT = Fb + 3 * FSZ;           // 196608
    float* el   = (float*)(W1bT + 3 * 65536);      // [3][N*H]
    float* er   = el + 3 * N_NODES * H;
    float* hA   = er + 3 * N_NODES * H;            // [N][32]
    float* hB   = hA + (size_t)N_NODES * D;
    float* wlr  = hB + (size_t)N_NODES * D;        // [6][2048]
    float* wlr2 = wlr + 6 * 2048;                  // [6][256]
    float* bs   = wlr2 + 6 * 256;                  // [4][32]
    int* off    = (int*)(bs + 128);                // 3N+1
    int* cursor = off + 3 * N_NODES + 1;
    int* cnt    = cursor + 3 * N_NODES;
    int* loc    = cnt + 3 * N_NODES;
    int* bsum   = loc + 3 * N_NODES;
    int* usort  = bsum + 128;                      // 3NE

    float* el0 = el, *el1p = el + N_NODES * H, *el2p = el + 2 * N_NODES * H;
    float* er0 = er, *er1p = er + N_NODES * H, *er2p = er + 2 * N_NODES * H;
    int* off0 = off, *off1 = off + N_NODES, *off2 = off + 2 * N_NODES;
    float* bsA1 = bs, *bsB1 = bs + 32, *bsA2 = bs + 64, *bsB2 = bs + 96;

    const dim3 GB_MM3(157, 4, 3);
    const dim3 GB_GV(N_NODES * H / 256, 2);        // 625 x 2
    const int GB_ALL = (2 * N_NODES + 3) / 4;      // 10000
    const int GB_3E  = (3 * NE + 255) / 256;
    const int PREP_B = 10247;

    // ---- CSR build + prep ----
    hipMemsetAsync(cnt, 0, SCAN_NT * sizeof(int), stream);
    hist3<<<GB_3E, 256, 0, stream>>>(v0, v1, v2, cnt);
    scan_blk<<<SCAN_NB, 512, 0, stream>>>(cnt, loc, bsum);
    scan_add2<<<SCAN_NB, 512, 0, stream>>>(loc, bsum, off, cursor);
    fill3<<<GB_3E, 256, 0, stream>>>(u0, v0, u1, v1, u2, v2, cursor, usort);
    prep<<<PREP_B, 256, 0, stream>>>(xA, xB, W1, al1, ar1, b1, W2, al2, ar2, b2,
                                     xAb, xBb, W1bT, bs, wlr, wlr2);

    // ---------------- layer 1 ----------------
    mfma_gemm3<<<GB_MM3, 256, 0, stream>>>(xAb, xBb, W1bT, Fb, N_NODES);
    gemv6<256><<<GB_GV, 256, 0, stream>>>(xA, xB, wlr, el, er, N_NODES);
    seg_att_all<1><<<GB_ALL, 256, 0, stream>>>(el0, er0, off0, F0b,
                                               el1p, er1p, off1, F1b,
                                               el2p, er2p, off2, F2b,
                                               usort, bsB1, bsA1, hB, hA, N_NODES);

    // ---------------- layer 2 ----------------
    gemm32_3<<<GB_MM3, 256, 0, stream>>>(hA, hB, W2, Fb, N_NODES);
    gemv6<32><<<GB_GV, 256, 0, stream>>>(hA, hB, wlr2, el, er, N_NODES);
    seg_att_all<0><<<GB_ALL, 256, 0, stream>>>(el0, er0, off0, F0b,
                                               el1p, er1p, off1, F1b,
                                               el2p, er2p, off2, F2b,
                                               usort, bsB2, bsA2,
                                               out + (size_t)N_NODES * D, out, N_NODES);
}

// Round 15
// 314.300 us; speedup vs baseline: 1.1687x; 1.1495x over previous
//
#include <hip/hip_runtime.h>
#include <float.h>

#define NEG_SLOPE 0.2f

constexpr int N_NODES = 20000;
constexpr int NE      = 320000;
constexpr int H       = 8;
constexpr int D       = 32;
constexpr int HD      = 256;   // H*D
constexpr int FIN     = 256;
constexpr int FSZi    = N_NODES * HD;          // 5,120,000
constexpr int CAP     = 96;                    // padded adjacency capacity (P(deg>=96)<1e-40)

typedef __attribute__((ext_vector_type(8))) short bf16x8;
typedef __attribute__((ext_vector_type(4))) float f32x4;

// ---- bf16 helpers (RNE) ----
__device__ __forceinline__ unsigned short f2bf(float x) {
    unsigned u = __float_as_uint(x);
    unsigned r = 0x7FFFu + ((u >> 16) & 1u);
    return (unsigned short)((u + r) >> 16);
}
__device__ __forceinline__ float bf2f(unsigned short h) {
    return __uint_as_float(((unsigned)h) << 16);
}

// ============ fused prep: cvt(xA,xB) | W1 transpose->bf16 | bias | wlr1 | wlr2 | zero cnt ============
__device__ __forceinline__ void wlr_calc(const float* W, const float* al,
                                         const float* ar, float* wlr,
                                         int K, int wstride, int t)
{
    int half = t / (3 * K * H);
    int rem  = t % (3 * K * H);
    int et = rem / (K * H);
    int rem2 = rem % (K * H);
    int k = rem2 / H, h = rem2 % H;
    const float* av = (half ? ar : al) + et * HD + h * D;
    const float* Wp = W + (size_t)et * wstride + k * HD + h * D;
    float s = 0.f;
#pragma unroll
    for (int d = 0; d < D; d++) s += Wp[d] * av[d];
    wlr[t] = s;
}

__global__ __launch_bounds__(256) void prep(
    const float* __restrict__ xA, const float* __restrict__ xB,
    const float* __restrict__ W1, const float* __restrict__ al1,
    const float* __restrict__ ar1, const float* __restrict__ b1,
    const float* __restrict__ W2, const float* __restrict__ al2,
    const float* __restrict__ ar2, const float* __restrict__ b2,
    unsigned short* __restrict__ xAb, unsigned short* __restrict__ xBb,
    unsigned short* __restrict__ W1bT, float* __restrict__ bs,
    float* __restrict__ wlr, float* __restrict__ wlr2, int* __restrict__ cnt)
{
    const int bid = blockIdx.x;
    const int tid = threadIdx.x;
    if (bid < 10000) {
        int t = bid * 1024 + tid * 4;
        const float* in; unsigned short* outp; int o;
        if (t < FSZi) { in = xA; outp = xAb; o = t; }
        else          { in = xB; outp = xBb; o = t - FSZi; }
        float4 v = *(const float4*)(in + o);
        ushort4 ob;
        ob.x = f2bf(v.x); ob.y = f2bf(v.y); ob.z = f2bf(v.z); ob.w = f2bf(v.w);
        *(ushort4*)(outp + o) = ob;
    } else if (bid < 10192) {
        int idx = (bid - 10000) * 256 + tid;          // [0,49152)
        int z = idx / 16384, rem = idx % 16384;
        int n = rem / 64, k4 = rem % 64;
        const float* Wz = W1 + (size_t)z * 65536;
        ushort4 ob;
        ob.x = f2bf(Wz[(k4 * 4 + 0) * 256 + n]);
        ob.y = f2bf(Wz[(k4 * 4 + 1) * 256 + n]);
        ob.z = f2bf(Wz[(k4 * 4 + 2) * 256 + n]);
        ob.w = f2bf(Wz[(k4 * 4 + 3) * 256 + n]);
        *(ushort4*)(W1bT + (size_t)z * 65536 + n * 256 + k4 * 4) = ob;
    } else if (bid == 10192) {
        if (tid < 128) {
            int which = tid >> 5, d = tid & 31;
            const float* b = (which < 2) ? b1 : b2;
            float s = 0.f;
            if (which & 1) {
#pragma unroll
                for (int h = 0; h < H; h++) s += b[0 * 256 + h * D + d];
            } else {
#pragma unroll
                for (int h = 0; h < H; h++) s += b[1 * 256 + h * D + d] + b[2 * 256 + h * D + d];
            }
            bs[tid] = s;
        }
    } else if (bid < 10241) {
        int t = (bid - 10193) * 256 + tid;            // [0,12288)
        wlr_calc(W1, al1, ar1, wlr, 256, 65536, t);
    } else if (bid < 10247) {
        int t = (bid - 10241) * 256 + tid;            // [0,1536)
        wlr_calc(W2, al2, ar2, wlr2, 32, 8192, t);
    } else {
        int idx = ((bid - 10247) * 256 + tid) * 4;    // zero cnt[3N]
        if (idx < 3 * N_NODES) {
            cnt[idx] = 0;
            if (idx + 1 < 3 * N_NODES) cnt[idx + 1] = 0;
            if (idx + 2 < 3 * N_NODES) cnt[idx + 2] = 0;
            if (idx + 3 < 3 * N_NODES) cnt[idx + 3] = 0;
        }
    }
}

// ============ direct padded-adjacency build (no scan) ============
__global__ void fill_direct(const int* __restrict__ u0, const int* __restrict__ v0,
                            const int* __restrict__ u1, const int* __restrict__ v1,
                            const int* __restrict__ u2, const int* __restrict__ v2,
                            int* __restrict__ cnt, int* __restrict__ usort)
{
    int t = blockIdx.x * blockDim.x + threadIdx.x;
    if (t >= 3 * NE) return;
    int et = t / NE, i = t - et * NE;
    const int* up = (et == 0) ? u0 : (et == 1) ? u1 : u2;
    const int* vp = (et == 0) ? v0 : (et == 1) ? v1 : v2;
    int node = et * N_NODES + vp[i];
    int slot = atomicAdd(&cnt[node], 1);
    usort[(size_t)node * CAP + slot] = up[i];
}

// ============ MFMA GEMM (z-batched): B direct from pre-transposed W ============
__global__ __launch_bounds__(256) void mfma_gemm3(
    const unsigned short* __restrict__ xAb, const unsigned short* __restrict__ xBb,
    const unsigned short* __restrict__ W1bT, unsigned short* __restrict__ Fb, int M)
{
    const int z = blockIdx.z;
    const unsigned short* Xb = (z == 1) ? xBb : xAb;
    const unsigned short* WzT = W1bT + (size_t)z * 65536;
    unsigned short* F = Fb + (size_t)z * FSZi;

    __shared__ unsigned short Xs[2][128][40];
    const int tid = threadIdx.x;
    const int wid = tid >> 6, lane = tid & 63;
    const int r0 = blockIdx.x * 128;
    const int c0 = blockIdx.y * 64;
    const int l15 = lane & 15, lg = lane >> 4;

    f32x4 acc[2][4];
#pragma unroll
    for (int i = 0; i < 2; i++)
#pragma unroll
        for (int j = 0; j < 4; j++) acc[i][j] = (f32x4){0.f, 0.f, 0.f, 0.f};

    const int srow = tid >> 2, sq = tid & 3;
    bf16x8 bcur[4], bnxt[4];

    {
        int grow0 = r0 + srow, grow1 = r0 + srow + 64;
        *(int4*)&Xs[0][srow][sq * 8] =
            (grow0 < M) ? *(const int4*)(Xb + (size_t)grow0 * FIN + sq * 8) : make_int4(0,0,0,0);
        *(int4*)&Xs[0][srow + 64][sq * 8] =
            (grow1 < M) ? *(const int4*)(Xb + (size_t)grow1 * FIN + sq * 8) : make_int4(0,0,0,0);
    }
#pragma unroll
    for (int j = 0; j < 4; j++)
        bcur[j] = *(const bf16x8*)(WzT + (size_t)(c0 + j * 16 + l15) * 256 + lg * 8);
    __syncthreads();

    for (int s = 0; s < 8; s++) {
        int cur = s & 1, nb = cur ^ 1;
        if (s < 7) {
            int kc = (s + 1) * 32;
            int grow0 = r0 + srow, grow1 = r0 + srow + 64;
            *(int4*)&Xs[nb][srow][sq * 8] =
                (grow0 < M) ? *(const int4*)(Xb + (size_t)grow0 * FIN + kc + sq * 8) : make_int4(0,0,0,0);
            *(int4*)&Xs[nb][srow + 64][sq * 8] =
                (grow1 < M) ? *(const int4*)(Xb + (size_t)grow1 * FIN + kc + sq * 8) : make_int4(0,0,0,0);
#pragma unroll
            for (int j = 0; j < 4; j++)
                bnxt[j] = *(const bf16x8*)(WzT + (size_t)(c0 + j * 16 + l15) * 256 + kc + lg * 8);
        }
        const int rm = wid * 32;
        bf16x8 a0 = *(const bf16x8*)&Xs[cur][rm + l15][lg * 8];
        bf16x8 a1 = *(const bf16x8*)&Xs[cur][rm + 16 + l15][lg * 8];
#pragma unroll
        for (int j = 0; j < 4; j++) {
            acc[0][j] = __builtin_amdgcn_mfma_f32_16x16x32_bf16(a0, bcur[j], acc[0][j], 0, 0, 0);
            acc[1][j] = __builtin_amdgcn_mfma_f32_16x16x32_bf16(a1, bcur[j], acc[1][j], 0, 0, 0);
        }
        __syncthreads();
#pragma unroll
        for (int j = 0; j < 4; j++) bcur[j] = bnxt[j];
    }
    const int rm = wid * 32;
#pragma unroll
    for (int i = 0; i < 2; i++)
#pragma unroll
        for (int j = 0; j < 4; j++)
#pragma unroll
            for (int r = 0; r < 4; r++) {
                int row = r0 + rm + i * 16 + lg * 4 + r;
                if (row < M)
                    F[(size_t)row * 256 + c0 + j * 16 + l15] = f2bf(acc[i][j][r]);
            }
}

// ============ layer-2 vector GEMM (z-batched) ============
__global__ __launch_bounds__(256) void gemm32_3(
    const float* __restrict__ hA, const float* __restrict__ hB,
    const float* __restrict__ W2, unsigned short* __restrict__ Fb, int M)
{
    const int z = blockIdx.z;
    const float* X = (z == 1) ? hB : hA;
    const float* W = W2 + (size_t)z * 8192;
    unsigned short* F = Fb + (size_t)z * FSZi;

    __shared__ float Xs[128][40];
    __shared__ float Ws[32][64];
    const int tx = threadIdx.x & 15;
    const int ty = threadIdx.x >> 4;
    const int r0 = blockIdx.x * 128;
    const int c0 = blockIdx.y * 64;
    for (int idx = threadIdx.x; idx < 128 * 8; idx += 256) {
        int row = idx >> 3, kq = idx & 7;
        int grow = r0 + row;
        float4 xv = (grow < M) ? *(const float4*)(X + (size_t)grow * 32 + kq * 4)
                               : make_float4(0.f, 0.f, 0.f, 0.f);
        *(float4*)&Xs[row][kq * 4] = xv;
    }
    for (int idx = threadIdx.x; idx < 32 * 16; idx += 256) {
        int k = idx >> 4, cq = idx & 15;
        *(float4*)&Ws[k][cq * 4] = *(const float4*)(W + (size_t)k * 256 + c0 + cq * 4);
    }
    __syncthreads();
    float4 acc[8];
#pragma unroll
    for (int r = 0; r < 8; r++) acc[r] = make_float4(0.f, 0.f, 0.f, 0.f);
#pragma unroll 4
    for (int k = 0; k < 32; k++) {
        float4 wv = *(float4*)&Ws[k][tx * 4];
#pragma unroll
        for (int r = 0; r < 8; r++) {
            float x = Xs[ty + 16 * r][k];
            acc[r].x = fmaf(x, wv.x, acc[r].x);
            acc[r].y = fmaf(x, wv.y, acc[r].y);
            acc[r].z = fmaf(x, wv.z, acc[r].z);
            acc[r].w = fmaf(x, wv.w, acc[r].w);
        }
    }
#pragma unroll
    for (int r = 0; r < 8; r++) {
        int row = r0 + ty + 16 * r;
        if (row < M) {
            ushort4 cb;
            cb.x = f2bf(acc[r].x); cb.y = f2bf(acc[r].y);
            cb.z = f2bf(acc[r].z); cb.w = f2bf(acc[r].w);
            *(ushort4*)(F + (size_t)row * 256 + c0 + tx * 4) = cb;
        }
    }
}

// ---- fused GEMVs: grid.y==0: xa -> el0,er1,el2,er2 ; grid.y==1: xb -> el1,er0 ----
template <int K>
__global__ __launch_bounds__(256) void gemv6(
    const float* __restrict__ xa, const float* __restrict__ xb,
    const float* __restrict__ wlr,
    float* __restrict__ el, float* __restrict__ er, int N)
{
    __shared__ float w[4][K * H];
    const int KH = K * H;
    const int NH = N_NODES * H;
    float *o0, *o1, *o2, *o3;
    const float* x;
    if (blockIdx.y == 0) {
        for (int i = threadIdx.x; i < KH; i += 256) {
            w[0][i] = wlr[0 * KH + i];
            w[1][i] = wlr[4 * KH + i];
            w[2][i] = wlr[2 * KH + i];
            w[3][i] = wlr[5 * KH + i];
        }
        x = xa;
        o0 = el; o1 = er + NH; o2 = el + 2 * NH; o3 = er + 2 * NH;
    } else {
        for (int i = threadIdx.x; i < KH; i += 256) {
            w[0][i] = wlr[1 * KH + i];
            w[1][i] = wlr[3 * KH + i];
        }
        x = xb;
        o0 = el + NH; o1 = er; o2 = nullptr; o3 = nullptr;
    }
    __syncthreads();
    int t = blockIdx.x * 256 + threadIdx.x;
    if (t >= N * H) return;
    int n = t >> 3, h = t & 7;
    const float4* xp = (const float4*)(x + (size_t)n * K);
    float s0 = 0.f, s1 = 0.f, s2 = 0.f, s3 = 0.f;
    if (blockIdx.y == 0) {
#pragma unroll 2
        for (int k4 = 0; k4 < K / 4; k4++) {
            float4 xv = xp[k4];
            const float* xe = &xv.x;
#pragma unroll
            for (int e = 0; e < 4; e++) {
                int idx = (4 * k4 + e) * H + h;
                float xx = xe[e];
                s0 = fmaf(xx, w[0][idx], s0);
                s1 = fmaf(xx, w[1][idx], s1);
                s2 = fmaf(xx, w[2][idx], s2);
                s3 = fmaf(xx, w[3][idx], s3);
            }
        }
        o0[t] = s0; o1[t] = s1; o2[t] = s2; o3[t] = s3;
    } else {
#pragma unroll 2
        for (int k4 = 0; k4 < K / 4; k4++) {
            float4 xv = xp[k4];
            const float* xe = &xv.x;
#pragma unroll
            for (int e = 0; e < 4; e++) {
                int idx = (4 * k4 + e) * H + h;
                float xx = xe[e];
                s0 = fmaf(xx, w[0][idx], s0);
                s1 = fmaf(xx, w[1][idx], s1);
            }
        }
        o0[t] = s0; o1[t] = s1;
    }
}

// ============ fused edge softmax + gather + head-mean (bf16 F, padded adjacency) ============

__device__ __forceinline__ float lrelu(float e) {
    return (e >= 0.f) ? e : NEG_SLOPE * e;
}

__device__ __forceinline__ float4 seg_accum(
    const float* __restrict__ el, float erh,
    const int* __restrict__ us, int lo, int hi,
    const unsigned short* __restrict__ Fs, int lane, int h)
{
    float4 aa = make_float4(0.f, 0.f, 0.f, 0.f);
    if (lo >= hi) return aa;
    const int q = lane & 7;
    const int lbase = lane & 56;   // h*8
    float s = 0.f;
    int j = lo;
    for (; j + 8 <= hi; j += 8) {
        int u[8];
#pragma unroll
        for (int qq = 0; qq < 8; qq++) u[qq] = us[j + qq];
        ushort4 fb[8];
#pragma unroll
        for (int qq = 0; qq < 8; qq++)
            fb[qq] = *(const ushort4*)(Fs + ((size_t)u[qq] << 8) + lane * 4);
        float myw = __expf(lrelu(el[u[q] * H + h] + erh));
#pragma unroll
        for (int qq = 0; qq < 8; qq++) {
            float w = __shfl(myw, lbase + qq, 64);
            s += w;
            aa.x = fmaf(w, bf2f(fb[qq].x), aa.x);
            aa.y = fmaf(w, bf2f(fb[qq].y), aa.y);
            aa.z = fmaf(w, bf2f(fb[qq].z), aa.z);
            aa.w = fmaf(w, bf2f(fb[qq].w), aa.w);
        }
    }
    if (j < hi) {
        int rem = hi - j;
        int u[8];
#pragma unroll
        for (int qq = 0; qq < 8; qq++) u[qq] = us[(qq < rem) ? j + qq : hi - 1];
        ushort4 fb[8];
#pragma unroll
        for (int qq = 0; qq < 8; qq++)
            fb[qq] = *(const ushort4*)(Fs + ((size_t)u[qq] << 8) + lane * 4);
        float myw = (q < rem) ? __expf(lrelu(el[u[q] * H + h] + erh)) : 0.f;
#pragma unroll
        for (int qq = 0; qq < 8; qq++) {
            float w = __shfl(myw, lbase + qq, 64);
            s += w;
            aa.x = fmaf(w, bf2f(fb[qq].x), aa.x);
            aa.y = fmaf(w, bf2f(fb[qq].y), aa.y);
            aa.z = fmaf(w, bf2f(fb[qq].z), aa.z);
            aa.w = fmaf(w, bf2f(fb[qq].w), aa.w);
        }
    }
    float inv = (s > 0.f) ? 1.f / s : 0.f;
    aa.x *= inv; aa.y *= inv; aa.z *= inv; aa.w *= inv;
    return aa;
}

template <int RELU>
__global__ __launch_bounds__(256) void seg_att_all(
    const float* __restrict__ el0, const float* __restrict__ er0,
    const unsigned short* __restrict__ F0,
    const float* __restrict__ el1, const float* __restrict__ er1,
    const unsigned short* __restrict__ F1,
    const float* __restrict__ el2, const float* __restrict__ er2,
    const unsigned short* __restrict__ F2,
    const int* __restrict__ cnt, const int* __restrict__ us,
    const float* __restrict__ bsB, const float* __restrict__ bsA,
    float* __restrict__ outB, float* __restrict__ outA, int N)
{
    int wid = blockIdx.x * 4 + (threadIdx.x >> 6);
    if (wid >= 2 * N) return;
    const int lane = threadIdx.x & 63;
    const int h = lane >> 3;
    float4 tot;
    const float* bs;
    float* out;
    int v;
    if (wid < N) {
        v = wid;
        int lo = v * CAP;
        tot = seg_accum(el0, er0[v * H + h], us, lo, lo + cnt[v], F0, lane, h);
        bs = bsB; out = outB;
    } else {
        v = wid - N;
        int lo1 = (N_NODES + v) * CAP;
        int lo2 = (2 * N_NODES + v) * CAP;
        float4 t1 = seg_accum(el1, er1[v * H + h], us, lo1, lo1 + cnt[N_NODES + v], F1, lane, h);
        float4 t2 = seg_accum(el2, er2[v * H + h], us, lo2, lo2 + cnt[2 * N_NODES + v], F2, lane, h);
        tot.x = t1.x + t2.x; tot.y = t1.y + t2.y;
        tot.z = t1.z + t2.z; tot.w = t1.w + t2.w;
        bs = bsA; out = outA;
    }
#pragma unroll
    for (int mask = 8; mask <= 32; mask <<= 1) {
        tot.x += __shfl_xor(tot.x, mask, 64);
        tot.y += __shfl_xor(tot.y, mask, 64);
        tot.z += __shfl_xor(tot.z, mask, 64);
        tot.w += __shfl_xor(tot.w, mask, 64);
    }
    if (lane < 8) {
        float4 b = *(const float4*)(bs + lane * 4);
        float4 o;
        o.x = (tot.x + b.x) * 0.125f;
        o.y = (tot.y + b.y) * 0.125f;
        o.z = (tot.z + b.z) * 0.125f;
        o.w = (tot.w + b.w) * 0.125f;
        if (RELU) {
            o.x = fmaxf(o.x, 0.f); o.y = fmaxf(o.y, 0.f);
            o.z = fmaxf(o.z, 0.f); o.w = fmaxf(o.w, 0.f);
        }
        *(float4*)(out + (size_t)v * D + lane * 4) = o;
    }
}

// ================= host =================

extern "C" void kernel_launch(void* const* d_in, const int* in_sizes, int n_in,
                              void* d_out, int out_size, void* d_ws, size_t ws_size,
                              hipStream_t stream)
{
    const float* xA  = (const float*)d_in[0];
    const float* xB  = (const float*)d_in[1];
    const float* W1  = (const float*)d_in[2];
    const float* al1 = (const float*)d_in[3];
    const float* ar1 = (const float*)d_in[4];
    const float* b1  = (const float*)d_in[5];
    const float* W2  = (const float*)d_in[6];
    const float* al2 = (const float*)d_in[7];
    const float* ar2 = (const float*)d_in[8];
    const float* b2  = (const float*)d_in[9];
    const int* u0 = (const int*)d_in[10];
    const int* v0 = (const int*)d_in[11];
    const int* u1 = (const int*)d_in[12];
    const int* v1 = (const int*)d_in[13];
    const int* u2 = (const int*)d_in[14];
    const int* v2 = (const int*)d_in[15];
    float* out = (float*)d_out;

    const size_t FSZ = (size_t)FSZi;
    unsigned short* xAb  = (unsigned short*)d_ws;
    unsigned short* xBb  = xAb + FSZ;
    unsigned short* Fb   = xBb + FSZ;              // [3][FSZ]
    unsigned short* F0b  = Fb;
    unsigned short* F1b  = Fb + FSZ;
    unsigned short* F2b  = Fb + 2 * FSZ;
    unsigned short* W1bT = Fb + 3 * FSZ;           // 196608
    float* el   = (float*)(W1bT + 3 * 65536);      // [3][N*H]
    float* er   = el + 3 * N_NODES * H;
    float* hA   = er + 3 * N_NODES * H;            // [N][32]
    float* hB   = hA + (size_t)N_NODES * D;
    float* wlr  = hB + (size_t)N_NODES * D;        // [6][2048]
    float* wlr2 = wlr + 6 * 2048;                  // [6][256]
    float* bs   = wlr2 + 6 * 256;                  // [4][32]
    int* cnt    = (int*)(bs + 128);                // 3N
    int* usort  = cnt + 3 * N_NODES;               // 3N*CAP

    float* el0 = el, *el1p = el + N_NODES * H, *el2p = el + 2 * N_NODES * H;
    float* er0 = er, *er1p = er + N_NODES * H, *er2p = er + 2 * N_NODES * H;
    float* bsA1 = bs, *bsB1 = bs + 32, *bsA2 = bs + 64, *bsB2 = bs + 96;

    const dim3 GB_MM3(157, 4, 3);
    const dim3 GB_GV(N_NODES * H / 256, 2);        // 625 x 2
    const int GB_ALL = (2 * N_NODES + 3) / 4;      // 10000
    const int GB_3E  = (3 * NE + 255) / 256;       // 3750
    const int PREP_B = 10247 + (3 * N_NODES / 1024 + 1);   // +59 zero-blocks

    // ---- prep (incl. cnt zeroing) + direct adjacency build ----
    prep<<<PREP_B, 256, 0, stream>>>(xA, xB, W1, al1, ar1, b1, W2, al2, ar2, b2,
                                     xAb, xBb, W1bT, bs, wlr, wlr2, cnt);
    fill_direct<<<GB_3E, 256, 0, stream>>>(u0, v0, u1, v1, u2, v2, cnt, usort);

    // ---------------- layer 1 ----------------
    mfma_gemm3<<<GB_MM3, 256, 0, stream>>>(xAb, xBb, W1bT, Fb, N_NODES);
    gemv6<256><<<GB_GV, 256, 0, stream>>>(xA, xB, wlr, el, er, N_NODES);
    seg_att_all<1><<<GB_ALL, 256, 0, stream>>>(el0, er0, F0b,
                                               el1p, er1p, F1b,
                                               el2p, er2p, F2b,
                                               cnt, usort, bsB1, bsA1, hB, hA, N_NODES);

    // ---------------- layer 2 ----------------
    gemm32_3<<<GB_MM3, 256, 0, stream>>>(hA, hB, W2, Fb, N_NODES);
    gemv6<32><<<GB_GV, 256, 0, stream>>>(hA, hB, wlr2, el, er, N_NODES);
    seg_att_all<0><<<GB_ALL, 256, 0, stream>>>(el0, er0, F0b,
                                               el1p, er1p, F1b,
                                               el2p, er2p, F2b,
                                               cnt, usort, bsB2, bsA2,
                                               out + (size_t)N_NODES * D, out, N_NODES);
}

// Round 16
// 281.441 us; speedup vs baseline: 1.3052x; 1.1168x over previous
//
#include <hip/hip_runtime.h>
#include <float.h>

#define NEG_SLOPE 0.2f

constexpr int N_NODES = 20000;
constexpr int NE      = 320000;
constexpr int H       = 8;
constexpr int D       = 32;
constexpr int HD      = 256;   // H*D
constexpr int FIN     = 256;
constexpr int FSZi    = N_NODES * HD;          // 5,120,000
constexpr int CAP     = 96;                    // padded adjacency capacity
constexpr int NBKT    = 80;                    // buckets of 256 nodes (v>>8)
constexpr int BKT_CAP = 5120;                  // mean 4096, sigma~64 -> 16 sigma

typedef __attribute__((ext_vector_type(8))) short bf16x8;
typedef __attribute__((ext_vector_type(4))) float f32x4;

// ---- bf16 helpers (RNE) ----
__device__ __forceinline__ unsigned short f2bf(float x) {
    unsigned u = __float_as_uint(x);
    unsigned r = 0x7FFFu + ((u >> 16) & 1u);
    return (unsigned short)((u + r) >> 16);
}
__device__ __forceinline__ float bf2f(unsigned short h) {
    return __uint_as_float(((unsigned)h) << 16);
}

// ============ fused prep: cvt(xA,xB) | W1 transpose->bf16 | bias | wlr1 | wlr2 | zero cur ============
__device__ __forceinline__ void wlr_calc(const float* W, const float* al,
                                         const float* ar, float* wlr,
                                         int K, int wstride, int t)
{
    int half = t / (3 * K * H);
    int rem  = t % (3 * K * H);
    int et = rem / (K * H);
    int rem2 = rem % (K * H);
    int k = rem2 / H, h = rem2 % H;
    const float* av = (half ? ar : al) + et * HD + h * D;
    const float* Wp = W + (size_t)et * wstride + k * HD + h * D;
    float s = 0.f;
#pragma unroll
    for (int d = 0; d < D; d++) s += Wp[d] * av[d];
    wlr[t] = s;
}

__global__ __launch_bounds__(256) void prep(
    const float* __restrict__ xA, const float* __restrict__ xB,
    const float* __restrict__ W1, const float* __restrict__ al1,
    const float* __restrict__ ar1, const float* __restrict__ b1,
    const float* __restrict__ W2, const float* __restrict__ al2,
    const float* __restrict__ ar2, const float* __restrict__ b2,
    unsigned short* __restrict__ xAb, unsigned short* __restrict__ xBb,
    unsigned short* __restrict__ W1bT, float* __restrict__ bs,
    float* __restrict__ wlr, float* __restrict__ wlr2, int* __restrict__ cur)
{
    const int bid = blockIdx.x;
    const int tid = threadIdx.x;
    if (bid < 10000) {
        int t = bid * 1024 + tid * 4;
        const float* in; unsigned short* outp; int o;
        if (t < FSZi) { in = xA; outp = xAb; o = t; }
        else          { in = xB; outp = xBb; o = t - FSZi; }
        float4 v = *(const float4*)(in + o);
        ushort4 ob;
        ob.x = f2bf(v.x); ob.y = f2bf(v.y); ob.z = f2bf(v.z); ob.w = f2bf(v.w);
        *(ushort4*)(outp + o) = ob;
    } else if (bid < 10192) {
        int idx = (bid - 10000) * 256 + tid;          // [0,49152)
        int z = idx / 16384, rem = idx % 16384;
        int n = rem / 64, k4 = rem % 64;
        const float* Wz = W1 + (size_t)z * 65536;
        ushort4 ob;
        ob.x = f2bf(Wz[(k4 * 4 + 0) * 256 + n]);
        ob.y = f2bf(Wz[(k4 * 4 + 1) * 256 + n]);
        ob.z = f2bf(Wz[(k4 * 4 + 2) * 256 + n]);
        ob.w = f2bf(Wz[(k4 * 4 + 3) * 256 + n]);
        *(ushort4*)(W1bT + (size_t)z * 65536 + n * 256 + k4 * 4) = ob;
    } else if (bid == 10192) {
        if (tid < 128) {
            int which = tid >> 5, d = tid & 31;
            const float* b = (which < 2) ? b1 : b2;
            float s = 0.f;
            if (which & 1) {
#pragma unroll
                for (int h = 0; h < H; h++) s += b[0 * 256 + h * D + d];
            } else {
#pragma unroll
                for (int h = 0; h < H; h++) s += b[1 * 256 + h * D + d] + b[2 * 256 + h * D + d];
            }
            bs[tid] = s;
        }
    } else if (bid < 10241) {
        int t = (bid - 10193) * 256 + tid;            // [0,12288)
        wlr_calc(W1, al1, ar1, wlr, 256, 65536, t);
    } else if (bid < 10247) {
        int t = (bid - 10241) * 256 + tid;            // [0,1536)
        wlr_calc(W2, al2, ar2, wlr2, 32, 8192, t);
    } else {
        if (tid < 3 * NBKT) cur[tid] = 0;
    }
}

// ============ adjacency build pass A: partition edges into 80 node-range buckets ============
__global__ __launch_bounds__(256) void bucket_a(
    const int* __restrict__ u0, const int* __restrict__ v0,
    const int* __restrict__ u1, const int* __restrict__ v1,
    const int* __restrict__ u2, const int* __restrict__ v2,
    int* __restrict__ cur, unsigned* __restrict__ bucketed)
{
    const int et = blockIdx.y;
    const int* up = (et == 0) ? u0 : (et == 1) ? u1 : u2;
    const int* vp = (et == 0) ? v0 : (et == 1) ? v1 : v2;
    const int CHUNK = NE / 32;                 // 10000
    const int e0 = blockIdx.x * CHUNK;
    __shared__ int hist[NBKT], base[NBKT], lcur[NBKT];
    if (threadIdx.x < NBKT) hist[threadIdx.x] = 0;
    __syncthreads();
    for (int i = e0 + threadIdx.x; i < e0 + CHUNK; i += 256)
        atomicAdd(&hist[vp[i] >> 8], 1);
    __syncthreads();
    if (threadIdx.x < NBKT) {
        base[threadIdx.x] = atomicAdd(&cur[et * NBKT + threadIdx.x], hist[threadIdx.x]);
        lcur[threadIdx.x] = 0;
    }
    __syncthreads();
    for (int i = e0 + threadIdx.x; i < e0 + CHUNK; i += 256) {
        int v = vp[i], u = up[i];
        int bkt = v >> 8;
        int pos = base[bkt] + atomicAdd(&lcur[bkt], 1);
        bucketed[(size_t)(et * NBKT + bkt) * BKT_CAP + pos] =
            ((unsigned)v << 16) | (unsigned)u;
    }
}

// ============ pass B: one block per (etype,bucket); LDS slot counters; L2-local usort writes ====
__global__ __launch_bounds__(256) void bucket_b(
    const int* __restrict__ cur, const unsigned* __restrict__ bucketed,
    int* __restrict__ cnt, int* __restrict__ usort)
{
    const int et = blockIdx.y, bkt = blockIdx.x;
    const int nbase = bkt << 8;
    __shared__ int cl[256];
    cl[threadIdx.x] = 0;
    __syncthreads();
    const int count = cur[et * NBKT + bkt];
    const unsigned* src = bucketed + (size_t)(et * NBKT + bkt) * BKT_CAP;
    for (int i = threadIdx.x; i < count; i += 256) {
        unsigned e = src[i];
        int v = (int)(e >> 16), u = (int)(e & 0xFFFFu);
        int slot = atomicAdd(&cl[v - nbase], 1);
        usort[(size_t)(et * N_NODES + v) * CAP + slot] = u;
    }
    __syncthreads();
    int node = nbase + threadIdx.x;
    if (node < N_NODES) cnt[et * N_NODES + node] = cl[threadIdx.x];
}

// ============ MFMA GEMM (z-batched): B direct from pre-transposed W ============
__global__ __launch_bounds__(256) void mfma_gemm3(
    const unsigned short* __restrict__ xAb, const unsigned short* __restrict__ xBb,
    const unsigned short* __restrict__ W1bT, unsigned short* __restrict__ Fb, int M)
{
    const int z = blockIdx.z;
    const unsigned short* Xb = (z == 1) ? xBb : xAb;
    const unsigned short* WzT = W1bT + (size_t)z * 65536;
    unsigned short* F = Fb + (size_t)z * FSZi;

    __shared__ unsigned short Xs[2][128][40];
    const int tid = threadIdx.x;
    const int wid = tid >> 6, lane = tid & 63;
    const int r0 = blockIdx.x * 128;
    const int c0 = blockIdx.y * 64;
    const int l15 = lane & 15, lg = lane >> 4;

    f32x4 acc[2][4];
#pragma unroll
    for (int i = 0; i < 2; i++)
#pragma unroll
        for (int j = 0; j < 4; j++) acc[i][j] = (f32x4){0.f, 0.f, 0.f, 0.f};

    const int srow = tid >> 2, sq = tid & 3;
    bf16x8 bcur[4], bnxt[4];

    {
        int grow0 = r0 + srow, grow1 = r0 + srow + 64;
        *(int4*)&Xs[0][srow][sq * 8] =
            (grow0 < M) ? *(const int4*)(Xb + (size_t)grow0 * FIN + sq * 8) : make_int4(0,0,0,0);
        *(int4*)&Xs[0][srow + 64][sq * 8] =
            (grow1 < M) ? *(const int4*)(Xb + (size_t)grow1 * FIN + sq * 8) : make_int4(0,0,0,0);
    }
#pragma unroll
    for (int j = 0; j < 4; j++)
        bcur[j] = *(const bf16x8*)(WzT + (size_t)(c0 + j * 16 + l15) * 256 + lg * 8);
    __syncthreads();

    for (int s = 0; s < 8; s++) {
        int cur2 = s & 1, nb = cur2 ^ 1;
        if (s < 7) {
            int kc = (s + 1) * 32;
            int grow0 = r0 + srow, grow1 = r0 + srow + 64;
            *(int4*)&Xs[nb][srow][sq * 8] =
                (grow0 < M) ? *(const int4*)(Xb + (size_t)grow0 * FIN + kc + sq * 8) : make_int4(0,0,0,0);
            *(int4*)&Xs[nb][srow + 64][sq * 8] =
                (grow1 < M) ? *(const int4*)(Xb + (size_t)grow1 * FIN + kc + sq * 8) : make_int4(0,0,0,0);
#pragma unroll
            for (int j = 0; j < 4; j++)
                bnxt[j] = *(const bf16x8*)(WzT + (size_t)(c0 + j * 16 + l15) * 256 + kc + lg * 8);
        }
        const int rm = wid * 32;
        bf16x8 a0 = *(const bf16x8*)&Xs[cur2][rm + l15][lg * 8];
        bf16x8 a1 = *(const bf16x8*)&Xs[cur2][rm + 16 + l15][lg * 8];
#pragma unroll
        for (int j = 0; j < 4; j++) {
            acc[0][j] = __builtin_amdgcn_mfma_f32_16x16x32_bf16(a0, bcur[j], acc[0][j], 0, 0, 0);
            acc[1][j] = __builtin_amdgcn_mfma_f32_16x16x32_bf16(a1, bcur[j], acc[1][j], 0, 0, 0);
        }
        __syncthreads();
#pragma unroll
        for (int j = 0; j < 4; j++) bcur[j] = bnxt[j];
    }
    const int rm = wid * 32;
#pragma unroll
    for (int i = 0; i < 2; i++)
#pragma unroll
        for (int j = 0; j < 4; j++)
#pragma unroll
            for (int r = 0; r < 4; r++) {
                int row = r0 + rm + i * 16 + lg * 4 + r;
                if (row < M)
                    F[(size_t)row * 256 + c0 + j * 16 + l15] = f2bf(acc[i][j][r]);
            }
}

// ============ layer-2 vector GEMM (z-batched) ============
__global__ __launch_bounds__(256) void gemm32_3(
    const float* __restrict__ hA, const float* __restrict__ hB,
    const float* __restrict__ W2, unsigned short* __restrict__ Fb, int M)
{
    const int z = blockIdx.z;
    const float* X = (z == 1) ? hB : hA;
    const float* W = W2 + (size_t)z * 8192;
    unsigned short* F = Fb + (size_t)z * FSZi;

    __shared__ float Xs[128][40];
    __shared__ float Ws[32][64];
    const int tx = threadIdx.x & 15;
    const int ty = threadIdx.x >> 4;
    const int r0 = blockIdx.x * 128;
    const int c0 = blockIdx.y * 64;
    for (int idx = threadIdx.x; idx < 128 * 8; idx += 256) {
        int row = idx >> 3, kq = idx & 7;
        int grow = r0 + row;
        float4 xv = (grow < M) ? *(const float4*)(X + (size_t)grow * 32 + kq * 4)
                               : make_float4(0.f, 0.f, 0.f, 0.f);
        *(float4*)&Xs[row][kq * 4] = xv;
    }
    for (int idx = threadIdx.x; idx < 32 * 16; idx += 256) {
        int k = idx >> 4, cq = idx & 15;
        *(float4*)&Ws[k][cq * 4] = *(const float4*)(W + (size_t)k * 256 + c0 + cq * 4);
    }
    __syncthreads();
    float4 acc[8];
#pragma unroll
    for (int r = 0; r < 8; r++) acc[r] = make_float4(0.f, 0.f, 0.f, 0.f);
#pragma unroll 4
    for (int k = 0; k < 32; k++) {
        float4 wv = *(float4*)&Ws[k][tx * 4];
#pragma unroll
        for (int r = 0; r < 8; r++) {
            float x = Xs[ty + 16 * r][k];
            acc[r].x = fmaf(x, wv.x, acc[r].x);
            acc[r].y = fmaf(x, wv.y, acc[r].y);
            acc[r].z = fmaf(x, wv.z, acc[r].z);
            acc[r].w = fmaf(x, wv.w, acc[r].w);
        }
    }
#pragma unroll
    for (int r = 0; r < 8; r++) {
        int row = r0 + ty + 16 * r;
        if (row < M) {
            ushort4 cb;
            cb.x = f2bf(acc[r].x); cb.y = f2bf(acc[r].y);
            cb.z = f2bf(acc[r].z); cb.w = f2bf(acc[r].w);
            *(ushort4*)(F + (size_t)row * 256 + c0 + tx * 4) = cb;
        }
    }
}

// ---- fused GEMVs: grid.y==0: xa -> el0,er1,el2,er2 ; grid.y==1: xb -> el1,er0 ----
template <int K>
__global__ __launch_bounds__(256) void gemv6(
    const float* __restrict__ xa, const float* __restrict__ xb,
    const float* __restrict__ wlr,
    float* __restrict__ el, float* __restrict__ er, int N)
{
    __shared__ float w[4][K * H];
    const int KH = K * H;
    const int NH = N_NODES * H;
    float *o0, *o1, *o2, *o3;
    const float* x;
    if (blockIdx.y == 0) {
        for (int i = threadIdx.x; i < KH; i += 256) {
            w[0][i] = wlr[0 * KH + i];
            w[1][i] = wlr[4 * KH + i];
            w[2][i] = wlr[2 * KH + i];
            w[3][i] = wlr[5 * KH + i];
        }
        x = xa;
        o0 = el; o1 = er + NH; o2 = el + 2 * NH; o3 = er + 2 * NH;
    } else {
        for (int i = threadIdx.x; i < KH; i += 256) {
            w[0][i] = wlr[1 * KH + i];
            w[1][i] = wlr[3 * KH + i];
        }
        x = xb;
        o0 = el + NH; o1 = er; o2 = nullptr; o3 = nullptr;
    }
    __syncthreads();
    int t = blockIdx.x * 256 + threadIdx.x;
    if (t >= N * H) return;
    int n = t >> 3, h = t & 7;
    const float4* xp = (const float4*)(x + (size_t)n * K);
    float s0 = 0.f, s1 = 0.f, s2 = 0.f, s3 = 0.f;
    if (blockIdx.y == 0) {
#pragma unroll 2
        for (int k4 = 0; k4 < K / 4; k4++) {
            float4 xv = xp[k4];
            const float* xe = &xv.x;
#pragma unroll
            for (int e = 0; e < 4; e++) {
                int idx = (4 * k4 + e) * H + h;
                float xx = xe[e];
                s0 = fmaf(xx, w[0][idx], s0);
                s1 = fmaf(xx, w[1][idx], s1);
                s2 = fmaf(xx, w[2][idx], s2);
                s3 = fmaf(xx, w[3][idx], s3);
            }
        }
        o0[t] = s0; o1[t] = s1; o2[t] = s2; o3[t] = s3;
    } else {
#pragma unroll 2
        for (int k4 = 0; k4 < K / 4; k4++) {
            float4 xv = xp[k4];
            const float* xe = &xv.x;
#pragma unroll
            for (int e = 0; e < 4; e++) {
                int idx = (4 * k4 + e) * H + h;
                float xx = xe[e];
                s0 = fmaf(xx, w[0][idx], s0);
                s1 = fmaf(xx, w[1][idx], s1);
            }
        }
        o0[t] = s0; o1[t] = s1;
    }
}

// ============ fused edge softmax + gather + head-mean (bf16 F, padded adjacency) ============

__device__ __forceinline__ float lrelu(float e) {
    return (e >= 0.f) ? e : NEG_SLOPE * e;
}

__device__ __forceinline__ float4 seg_accum(
    const float* __restrict__ el, float erh,
    const int* __restrict__ us, int lo, int hi,
    const unsigned short* __restrict__ Fs, int lane, int h)
{
    float4 aa = make_float4(0.f, 0.f, 0.f, 0.f);
    if (lo >= hi) return aa;
    const int q = lane & 7;
    const int lbase = lane & 56;   // h*8
    float s = 0.f;
    int j = lo;
    for (; j + 8 <= hi; j += 8) {
        int u[8];
#pragma unroll
        for (int qq = 0; qq < 8; qq++) u[qq] = us[j + qq];
        ushort4 fb[8];
#pragma unroll
        for (int qq = 0; qq < 8; qq++)
            fb[qq] = *(const ushort4*)(Fs + ((size_t)u[qq] << 8) + lane * 4);
        float myw = __expf(lrelu(el[u[q] * H + h] + erh));
#pragma unroll
        for (int qq = 0; qq < 8; qq++) {
            float w = __shfl(myw, lbase + qq, 64);
            s += w;
            aa.x = fmaf(w, bf2f(fb[qq].x), aa.x);
            aa.y = fmaf(w, bf2f(fb[qq].y), aa.y);
            aa.z = fmaf(w, bf2f(fb[qq].z), aa.z);
            aa.w = fmaf(w, bf2f(fb[qq].w), aa.w);
        }
    }
    if (j < hi) {
        int rem = hi - j;
        int u[8];
#pragma unroll
        for (int qq = 0; qq < 8; qq++) u[qq] = us[(qq < rem) ? j + qq : hi - 1];
        ushort4 fb[8];
#pragma unroll
        for (int qq = 0; qq < 8; qq++)
            fb[qq] = *(const ushort4*)(Fs + ((size_t)u[qq] << 8) + lane * 4);
        float myw = (q < rem) ? __expf(lrelu(el[u[q] * H + h] + erh)) : 0.f;
#pragma unroll
        for (int qq = 0; qq < 8; qq++) {
            float w = __shfl(myw, lbase + qq, 64);
            s += w;
            aa.x = fmaf(w, bf2f(fb[qq].x), aa.x);
            aa.y = fmaf(w, bf2f(fb[qq].y), aa.y);
            aa.z = fmaf(w, bf2f(fb[qq].z), aa.z);
            aa.w = fmaf(w, bf2f(fb[qq].w), aa.w);
        }
    }
    float inv = (s > 0.f) ? 1.f / s : 0.f;
    aa.x *= inv; aa.y *= inv; aa.z *= inv; aa.w *= inv;
    return aa;
}

template <int RELU>
__global__ __launch_bounds__(256) void seg_att_all(
    const float* __restrict__ el0, const float* __restrict__ er0,
    const unsigned short* __restrict__ F0,
    const float* __restrict__ el1, const float* __restrict__ er1,
    const unsigned short* __restrict__ F1,
    const float* __restrict__ el2, const float* __restrict__ er2,
    const unsigned short* __restrict__ F2,
    const int* __restrict__ cnt, const int* __restrict__ us,
    const float* __restrict__ bsB, const float* __restrict__ bsA,
    float* __restrict__ outB, float* __restrict__ outA, int N)
{
    int wid = blockIdx.x * 4 + (threadIdx.x >> 6);
    if (wid >= 2 * N) return;
    const int lane = threadIdx.x & 63;
    const int h = lane >> 3;
    float4 tot;
    const float* bs;
    float* out;
    int v;
    if (wid < N) {
        v = wid;
        int lo = v * CAP;
        tot = seg_accum(el0, er0[v * H + h], us, lo, lo + cnt[v], F0, lane, h);
        bs = bsB; out = outB;
    } else {
        v = wid - N;
        int lo1 = (N_NODES + v) * CAP;
        int lo2 = (2 * N_NODES + v) * CAP;
        float4 t1 = seg_accum(el1, er1[v * H + h], us, lo1, lo1 + cnt[N_NODES + v], F1, lane, h);
        float4 t2 = seg_accum(el2, er2[v * H + h], us, lo2, lo2 + cnt[2 * N_NODES + v], F2, lane, h);
        tot.x = t1.x + t2.x; tot.y = t1.y + t2.y;
        tot.z = t1.z + t2.z; tot.w = t1.w + t2.w;
        bs = bsA; out = outA;
    }
#pragma unroll
    for (int mask = 8; mask <= 32; mask <<= 1) {
        tot.x += __shfl_xor(tot.x, mask, 64);
        tot.y += __shfl_xor(tot.y, mask, 64);
        tot.z += __shfl_xor(tot.z, mask, 64);
        tot.w += __shfl_xor(tot.w, mask, 64);
    }
    if (lane < 8) {
        float4 b = *(const float4*)(bs + lane * 4);
        float4 o;
        o.x = (tot.x + b.x) * 0.125f;
        o.y = (tot.y + b.y) * 0.125f;
        o.z = (tot.z + b.z) * 0.125f;
        o.w = (tot.w + b.w) * 0.125f;
        if (RELU) {
            o.x = fmaxf(o.x, 0.f); o.y = fmaxf(o.y, 0.f);
            o.z = fmaxf(o.z, 0.f); o.w = fmaxf(o.w, 0.f);
        }
        *(float4*)(out + (size_t)v * D + lane * 4) = o;
    }
}

// ================= host =================

extern "C" void kernel_launch(void* const* d_in, const int* in_sizes, int n_in,
                              void* d_out, int out_size, void* d_ws, size_t ws_size,
                              hipStream_t stream)
{
    const float* xA  = (const float*)d_in[0];
    const float* xB  = (const float*)d_in[1];
    const float* W1  = (const float*)d_in[2];
    const float* al1 = (const float*)d_in[3];
    const float* ar1 = (const float*)d_in[4];
    const float* b1  = (const float*)d_in[5];
    const float* W2  = (const float*)d_in[6];
    const float* al2 = (const float*)d_in[7];
    const float* ar2 = (const float*)d_in[8];
    const float* b2  = (const float*)d_in[9];
    const int* u0 = (const int*)d_in[10];
    const int* v0 = (const int*)d_in[11];
    const int* u1 = (const int*)d_in[12];
    const int* v1 = (const int*)d_in[13];
    const int* u2 = (const int*)d_in[14];
    const int* v2 = (const int*)d_in[15];
    float* out = (float*)d_out;

    const size_t FSZ = (size_t)FSZi;
    unsigned short* xAb  = (unsigned short*)d_ws;
    unsigned short* xBb  = xAb + FSZ;
    unsigned short* Fb   = xBb + FSZ;              // [3][FSZ]
    unsigned short* F0b  = Fb;
    unsigned short* F1b  = Fb + FSZ;
    unsigned short* F2b  = Fb + 2 * FSZ;
    unsigned short* W1bT = Fb + 3 * FSZ;           // 196608
    float* el   = (float*)(W1bT + 3 * 65536);      // [3][N*H]
    float* er   = el + 3 * N_NODES * H;
    float* hA   = er + 3 * N_NODES * H;            // [N][32]
    float* hB   = hA + (size_t)N_NODES * D;
    float* wlr  = hB + (size_t)N_NODES * D;        // [6][2048]
    float* wlr2 = wlr + 6 * 2048;                  // [6][256]
    float* bs   = wlr2 + 6 * 256;                  // [4][32]
    int* cnt    = (int*)(bs + 128);                // 3N
    int* cur    = cnt + 3 * N_NODES;               // 3*NBKT
    unsigned* bucketed = (unsigned*)(cur + 3 * NBKT);  // 3*NBKT*BKT_CAP
    int* usort  = (int*)(bucketed + (size_t)3 * NBKT * BKT_CAP);  // 3N*CAP

    float* el0 = el, *el1p = el + N_NODES * H, *el2p = el + 2 * N_NODES * H;
    float* er0 = er, *er1p = er + N_NODES * H, *er2p = er + 2 * N_NODES * H;
    float* bsA1 = bs, *bsB1 = bs + 32, *bsA2 = bs + 64, *bsB2 = bs + 96;

    const dim3 GB_MM3(157, 4, 3);
    const dim3 GB_GV(N_NODES * H / 256, 2);        // 625 x 2
    const dim3 GB_BA(32, 3);                       // pass A
    const dim3 GB_BB(NBKT, 3);                     // pass B
    const int GB_ALL = (2 * N_NODES + 3) / 4;      // 10000
    const int PREP_B = 10248;

    // ---- prep (incl. cur zeroing) + bucketed adjacency build ----
    prep<<<PREP_B, 256, 0, stream>>>(xA, xB, W1, al1, ar1, b1, W2, al2, ar2, b2,
                                     xAb, xBb, W1bT, bs, wlr, wlr2, cur);
    bucket_a<<<GB_BA, 256, 0, stream>>>(u0, v0, u1, v1, u2, v2, cur, bucketed);
    bucket_b<<<GB_BB, 256, 0, stream>>>(cur, bucketed, cnt, usort);

    // ---------------- layer 1 ----------------
    mfma_gemm3<<<GB_MM3, 256, 0, stream>>>(xAb, xBb, W1bT, Fb, N_NODES);
    gemv6<256><<<GB_GV, 256, 0, stream>>>(xA, xB, wlr, el, er, N_NODES);
    seg_att_all<1><<<GB_ALL, 256, 0, stream>>>(el0, er0, F0b,
                                               el1p, er1p, F1b,
                                               el2p, er2p, F2b,
                                               cnt, usort, bsB1, bsA1, hB, hA, N_NODES);

    // ---------------- layer 2 ----------------
    gemm32_3<<<GB_MM3, 256, 0, stream>>>(hA, hB, W2, Fb, N_NODES);
    gemv6<32><<<GB_GV, 256, 0, stream>>>(hA, hB, wlr2, el, er, N_NODES);
    seg_att_all<0><<<GB_ALL, 256, 0, stream>>>(el0, er0, F0b,
                                               el1p, er1p, F1b,
                                               el2p, er2p, F2b,
                                               cnt, usort, bsB2, bsA2,
                                               out + (size_t)N_NODES * D, out, N_NODES);
}